// Round 8
// baseline (598.965 us; speedup 1.0000x reference)
//
#include <hip/hip_runtime.h>
#include <cstdint>
#include <cstddef>

typedef __attribute__((ext_vector_type(8))) short short8;
typedef __attribute__((ext_vector_type(4))) short short4v;
typedef __attribute__((ext_vector_type(4))) float float4v;

#define DEV static __device__ __forceinline__

DEV float b2f(unsigned short u) { return __uint_as_float(((unsigned int)u) << 16); }
DEV unsigned short f2b(float f) {
  unsigned int u = __float_as_uint(f);
  u = (u + 0x7fffu + ((u >> 16) & 1u)) >> 16;
  return (unsigned short)u;
}

#define MFMA32(a, b, c) __builtin_amdgcn_mfma_f32_16x16x32_bf16(a, b, c, 0, 0, 0)

// ---- problem sizes ----
static constexpr int NP   = 12416;  // qkvz stride: 8192 qkv + 4096 z + 32 a + 32 b + 64 pad
static constexpr int NPAD = 12544;  // wcat rows padded to 49*256 for 256-tile GEMM

// ---- ws layout (bytes), lifetime-overlaid; peak ~162 MB ----
static constexpr size_t OFF_QKVZ = 0;
static constexpr size_t SZ_QKVZ  = (size_t)4096*NP*2;        // 101,711,872
static constexpr size_t OFF_XB   = SZ_QKVZ;
static constexpr size_t SZ_XB    = (size_t)4096*2048*2;      // 16,777,216
static constexpr size_t OFF_WCAT = OFF_XB + SZ_XB;
static constexpr size_t SZ_WCAT  = (size_t)NPAD*2048*2;      // 51,380,224
static constexpr size_t OFF_QKVS = OFF_XB;                   // overlays xb+wcat after GEMM1
static constexpr size_t SZ_QKVS  = (size_t)4096*8192*2;      // 67,108,864
static constexpr size_t OFF_G    = OFF_XB + SZ_QKVS;         // fits in gap before wcat end
static constexpr size_t OFF_BET  = OFF_G + (size_t)4096*32*4;
static constexpr size_t OFF_YN   = OFF_XB;                   // after scan
static constexpr size_t SZ_YN    = (size_t)4096*4096*2;
static constexpr size_t OFF_WOB  = OFF_YN + SZ_YN;
static constexpr size_t WS_NEED  = OFF_WCAT + SZ_WCAT;       // 169,869,312

// ---- helpers ----
DEV void gl16(const unsigned short* g, char* l) {
  __builtin_amdgcn_global_load_lds((const __attribute__((address_space(1))) unsigned int*)g,
                                   (__attribute__((address_space(3))) unsigned int*)l,
                                   16, 0, 0);
}

DEV void store_out(unsigned short* C, size_t off, float v) { C[off] = f2b(v); }
DEV void store_out(float* C, size_t off, float v)          { C[off] = v; }

// ---- generic cast fp32 -> bf16 (n multiple of 4) ----
__global__ void castk(const float* __restrict__ in, unsigned short* __restrict__ out, int n4) {
  int idx = blockIdx.x * 256 + threadIdx.x;
  if (idx >= n4) return;
  float4v v = ((const float4v*)in)[idx];
  short4v o;
  o[0] = (short)f2b(v[0]); o[1] = (short)f2b(v[1]);
  o[2] = (short)f2b(v[2]); o[3] = (short)f2b(v[3]);
  ((short4v*)out)[idx] = o;
}

// ---- build concatenated weight [12544][2048] bf16 ----
__global__ void prep_wcat(const float* __restrict__ Wqkv, const float* __restrict__ Wz,
                          const float* __restrict__ Wa, const float* __restrict__ Wb,
                          unsigned short* __restrict__ Wcat) {
  size_t e4 = (size_t)blockIdx.x * 256 + threadIdx.x;
  if (e4 >= (size_t)NPAD * 2048 / 4) return;
  size_t e = e4 * 4;
  int row = (int)(e >> 11);
  int col = (int)(e & 2047);
  float4v v;
  if (row < 8192)       v = *(const float4v*)&Wqkv[(size_t)row * 2048 + col];
  else if (row < 12288) v = *(const float4v*)&Wz[(size_t)(row - 8192) * 2048 + col];
  else if (row < 12320) v = *(const float4v*)&Wa[(size_t)(row - 12288) * 2048 + col];
  else if (row < 12352) v = *(const float4v*)&Wb[(size_t)(row - 12320) * 2048 + col];
  else                  v = (float4v){0.f, 0.f, 0.f, 0.f};
  short4v o;
  o[0] = (short)f2b(v[0]); o[1] = (short)f2b(v[1]);
  o[2] = (short)f2b(v[2]); o[3] = (short)f2b(v[3]);
  *(short4v*)&Wcat[e] = o;
}

// ========= BM x 256 ring-pipelined bf16 MFMA GEMM (BK=32, 4-slot ring) ======
// C[M][NC] = A[M][K] @ B[N][K]^T. 512 thr = 8 waves (2M x 4N at BM=256).
// Ring of 4 K-tile slots: while computing K-tile j, stage K-tile j+3 (its slot
// was freed at the end of j-1). End-of-K-tile wait = counted vmcnt(2*TL):
// K-tile j+1 guaranteed landed while 2 K-tiles of loads stay in flight across
// the barrier (T4 mechanism — never drain to 0 in the main loop). Tail (last
// 3 K-tiles) drains with vmcnt(0). BK=32 row stride (64B) makes un-swizzled
// fragment ds_reads structurally conflict-free (8 words/bank uniform).
template <int BM, bool BNMAJOR, typename OutT>
__global__ __launch_bounds__(512, 2)
void gemm_ring(const unsigned short* __restrict__ A, const unsigned short* __restrict__ B,
               OutT* __restrict__ C, int K, int nbm, int nbn, int NC) {
  constexpr int MH   = BM / 128;          // 2 (BM=256) or 1 (BM=128)
  constexpr int AL   = BM / 128;          // gl16 rounds per A K-tile
  constexpr int BL   = 2;                 // gl16 rounds per B K-tile
  constexpr int TL   = AL + BL;           // loads per thread per K-tile
  constexpr int ASZ  = BM * 64;           // bytes: BM rows x 32 bf16
  constexpr int SLOT = ASZ + 16384;       // + B: 256 rows x 32 bf16
  __shared__ __align__(16) char sm[4 * SLOT];
  const int t = threadIdx.x;
  const int cpx = gridDim.x >> 3;
  int wg = blockIdx.x;
  wg = (wg & 7) * cpx + (wg >> 3);        // bijective XCD swizzle (grid % 8 == 0)
  const int bm = BNMAJOR ? (wg % nbm) : (wg / nbn);
  const int bn = BNMAJOR ? (wg / nbm) : (wg % nbn);

  const int wv = t >> 6, lane = t & 63;
  const int l16 = lane & 15, lg = lane >> 4;
  const int wm = (wv >> 2) * (BM / 2);
  const int wn = (wv & 3) * 64;

  size_t aoff[AL], boff[BL];
#pragma unroll
  for (int r = 0; r < AL; r++) {
    int L = r * 8192 + t * 16;
    aoff[r] = (size_t)(bm * BM + (L >> 6)) * K + ((L & 63) >> 1);
  }
#pragma unroll
  for (int r = 0; r < BL; r++) {
    int L = r * 8192 + t * 16;
    boff[r] = (size_t)(bn * 256 + (L >> 6)) * K + ((L & 63) >> 1);
  }

  float4v acc[MH * 4][4] = {};
  const int NKT = K >> 5;

#define STAGE(j)                                                              \
  do {                                                                        \
    const size_t ko = (size_t)(j) * 32;                                       \
    char* slot = sm + ((j) & 3) * SLOT;                                       \
    _Pragma("unroll") for (int r = 0; r < AL; r++)                            \
        gl16(A + aoff[r] + ko, slot + r * 8192 + t * 16);                     \
    _Pragma("unroll") for (int r = 0; r < BL; r++)                            \
        gl16(B + boff[r] + ko, slot + ASZ + r * 8192 + t * 16);               \
  } while (0)

#define COMPUTE(j)                                                            \
  do {                                                                        \
    char* ab = sm + ((j) & 3) * SLOT;                                         \
    char* bb = ab + ASZ;                                                      \
    short8 av[4], bv[4];                                                      \
    _Pragma("unroll") for (int nn = 0; nn < 4; nn++)                          \
        bv[nn] = *(const short8*)(bb + (wn + nn * 16 + l16) * 64 + lg * 16);  \
    _Pragma("unroll") for (int mi = 0; mi < 4; mi++)                          \
        av[mi] = *(const short8*)(ab + (wm + mi * 16 + l16) * 64 + lg * 16);  \
    __builtin_amdgcn_s_setprio(1);                                            \
    _Pragma("unroll") for (int mi = 0; mi < 4; mi++)                          \
    _Pragma("unroll") for (int nn = 0; nn < 4; nn++)                          \
        acc[mi][nn] = MFMA32(av[mi], bv[nn], acc[mi][nn]);                    \
    __builtin_amdgcn_s_setprio(0);                                            \
    if constexpr (MH == 2) {                                                  \
      _Pragma("unroll") for (int mi = 0; mi < 4; mi++)                        \
          av[mi] = *(const short8*)(ab + (wm + 64 + mi * 16 + l16) * 64 + lg * 16); \
      __builtin_amdgcn_s_setprio(1);                                          \
      _Pragma("unroll") for (int mi = 0; mi < 4; mi++)                        \
      _Pragma("unroll") for (int nn = 0; nn < 4; nn++)                        \
          acc[4 + mi][nn] = MFMA32(av[mi], bv[nn], acc[4 + mi][nn]);          \
      __builtin_amdgcn_s_setprio(0);                                          \
    }                                                                         \
  } while (0)

  // prologue: stage K-tiles 0..2; wait for K-tile 0 (2 tiles stay in flight)
  STAGE(0);
  STAGE(1);
  STAGE(2);
  asm volatile("s_waitcnt vmcnt(%0)" ::"n"(2 * TL) : "memory");
  __builtin_amdgcn_s_barrier();
  __builtin_amdgcn_sched_barrier(0);

  // main loop: counted vmcnt — never drains to 0
  for (int j = 0; j < NKT - 3; j++) {
    STAGE(j + 3);
    COMPUTE(j);
    asm volatile("s_waitcnt vmcnt(%0)" ::"n"(2 * TL) : "memory");
    __builtin_amdgcn_s_barrier();
    __builtin_amdgcn_sched_barrier(0);
  }
  // tail: last 3 K-tiles, full drain
  for (int j = NKT - 3; j < NKT; j++) {
    COMPUTE(j);
    asm volatile("s_waitcnt vmcnt(0)" ::: "memory");
    __builtin_amdgcn_s_barrier();
    __builtin_amdgcn_sched_barrier(0);
  }
#undef STAGE
#undef COMPUTE

  // epilogue
#pragma unroll
  for (int m = 0; m < MH * 4; m++) {
    int row0 = bm * BM + wm + m * 16 + lg * 4;
#pragma unroll
    for (int n = 0; n < 4; n++) {
      int col = bn * 256 + wn + n * 16 + l16;
      if (col < NC) {
#pragma unroll
        for (int rr = 0; rr < 4; rr++)
          store_out(C, (size_t)(row0 + rr) * NC + col, acc[m][n][rr]);
      }
    }
  }
}

// ---- conv(KW=4) + silu + q/k L2-norm, time-chunked (halo L1-reuse) ----
__global__ __launch_bounds__(1024)
void conv_silu_norm(const unsigned short* __restrict__ qkvz, const float* __restrict__ conv_w,
                    unsigned short* __restrict__ qkvs) {
  const int blk = blockIdx.x;
  const int b = blk >> 6;
  const int s0 = (blk & 63) << 4;
  const int t = threadIdx.x;
  const int c0 = t * 8;
  float w[8][4];
#pragma unroll
  for (int e = 0; e < 8; e++) {
    float4v wv = *(const float4v*)&conv_w[(c0 + e) * 4];
    w[e][0] = wv[0]; w[e][1] = wv[1]; w[e][2] = wv[2]; w[e][3] = wv[3];
  }
  const size_t base = (size_t)(b << 10) * NP + c0;
  const bool qk = c0 < 4096;
  const float qsc = (c0 < 2048) ? 0.08838834764831845f : 1.f;
#pragma unroll 1
  for (int i = 0; i < 16; i++) {
    const int s = s0 + i;
    float acc[8] = {0.f, 0.f, 0.f, 0.f, 0.f, 0.f, 0.f, 0.f};
#pragma unroll
    for (int j = 0; j < 4; j++) {
      const int sj = s - 3 + j;
      if (sj >= 0) {
        short8 v8 = *(const short8*)&qkvz[base + (size_t)sj * NP];
#pragma unroll
        for (int e = 0; e < 8; e++) acc[e] = fmaf(b2f((unsigned short)v8[e]), w[e][j], acc[e]);
      }
    }
    float out[8];
#pragma unroll
    for (int e = 0; e < 8; e++) { float xv = acc[e]; out[e] = xv * (1.f / (1.f + expf(-xv))); }
    if (qk) {
      float ss = 0.f;
#pragma unroll
      for (int e = 0; e < 8; e++) ss += out[e] * out[e];
      ss += __shfl_xor(ss, 1); ss += __shfl_xor(ss, 2);
      ss += __shfl_xor(ss, 4); ss += __shfl_xor(ss, 8);
      float sc = rsqrtf(ss + 1e-6f) * qsc;
#pragma unroll
      for (int e = 0; e < 8; e++) out[e] *= sc;
    }
    short8 o;
#pragma unroll
    for (int e = 0; e < 8; e++) o[e] = (short)f2b(out[e]);
    *(short8*)&qkvs[(size_t)((b << 10) + s) * 8192 + c0] = o;
  }
}

// ---- conv_state output: (B,CI,KW) fp32 from pre-conv qkv ----
__global__ void conv_state_k(const unsigned short* __restrict__ qkvz, float* __restrict__ cs) {
  int idx = blockIdx.x * 256 + threadIdx.x;  // < 131072 = 4*8192*4
  int b = idx >> 15;
  int rem = idx & 32767;
  int c = rem >> 2;
  int j = rem & 3;
  cs[idx] = b2f(qkvz[(size_t)(b * 1024 + 1020 + j) * NP + c]);
}

// ---- g / beta from a,b columns ----
__global__ void gb_kernel(const unsigned short* __restrict__ qkvz, const float* __restrict__ A_log,
                          const float* __restrict__ dt_bias, float* __restrict__ g,
                          float* __restrict__ bet) {
  int idx = blockIdx.x * 256 + threadIdx.x;  // < 4096*64
  int m = idx >> 6, n = idx & 63;
  if (n < 32) {
    float a = b2f(qkvz[(size_t)m * NP + 12288 + n]) + dt_bias[n];
    float sp = (a > 20.f) ? a : log1pf(expf(a));
    g[m * 32 + n] = -expf(A_log[n]) * sp;
  } else {
    int nn = n - 32;
    float bb = b2f(qkvz[(size_t)m * NP + 12320 + nn]);
    bet[m * 32 + nn] = 1.f / (1.f + expf(-bb));
  }
}

// ---- chunked delta-rule scan (UT transform), C=64, MFMA throughout ----
__global__ __launch_bounds__(256)
void scan_chunk(const unsigned short* __restrict__ qkvs, const float* __restrict__ g,
                const float* __restrict__ bet, unsigned short* __restrict__ y,
                float* __restrict__ state_out) {
  __shared__ __align__(16) unsigned short Kb[64][128];
  __shared__ __align__(16) unsigned short Qb[64][128];
  __shared__ __align__(16) unsigned short Sb[64][128];
  __shared__ __align__(16) unsigned short Ktt[128][64];
  __shared__ __align__(16) unsigned short Mb[64][64];
  __shared__ __align__(16) unsigned short Nb[64][64];
  __shared__ __align__(16) unsigned short Dbf[64][64];
  __shared__ __align__(16) unsigned short Vt[64][64];   // also reused as obuf
  __shared__ __align__(16) unsigned short Tb[4][16][16];
  __shared__ __align__(16) unsigned short rtmp[64][16];
  __shared__ float Gar[64];
  __shared__ float gamv[64];
  __shared__ float barr[64];
  __shared__ float gcs[2];

  const int bid = blockIdx.x;
  const int b = bid >> 6;
  const int h = (bid >> 1) & 31;
  const int half = bid & 1;
  const int hk = h >> 1;
  const int t = threadIdx.x;
  const int wv = t >> 6, lane = t & 63;
  const int l16 = lane & 15, lg = lane >> 4;
  const int bS = b << 10;

  float4v accS[8] = {};
  for (int idx = t; idx < 64 * 128; idx += 256) (&Sb[0][0])[idx] = 0;

  for (int ch = 0; ch < 16; ch++) {
    const int s0 = ch << 6;
    // ---- phase 1: stage Kb, Qb (swizzled via source permutation), Vt, g/beta ----
    {
#pragma unroll
      for (int rep = 0; rep < 4; rep++) {
        int rb = wv * 16 + rep * 4;
        int i = rb + (lane >> 4);
        int cg = (lane & 15) ^ (i & 7);
        const unsigned short* gk = qkvs + (size_t)(bS + s0 + i) * 8192 + 2048 + hk * 128 + cg * 8;
        gl16(gk, (char*)(&Kb[rb][0] + lane * 8));
        const unsigned short* gq = qkvs + (size_t)(bS + s0 + i) * 8192 + hk * 128 + cg * 8;
        gl16(gq, (char*)(&Qb[rb][0] + lane * 8));
      }
    }
    {
      int tt = t >> 2, q4 = t & 3;
      const unsigned short* gv = qkvs + (size_t)(bS + s0 + tt) * 8192 + 4096 + h * 128 + half * 64 + q4 * 16;
      short8 v0 = *(const short8*)gv;
      short8 v1 = *(const short8*)(gv + 8);
#pragma unroll
      for (int e = 0; e < 8; e++) {
        int v = q4 * 16 + e;
        Vt[v][tt ^ ((v & 7) << 3)] = (unsigned short)v0[e];
        v = q4 * 16 + 8 + e;
        Vt[v][tt ^ ((v & 7) << 3)] = (unsigned short)v1[e];
      }
    }
    if (t < 64) {
      float gt = g[(bS + s0 + t) * 32 + h];
      float bt = bet[(bS + s0 + t) * 32 + h];
#pragma unroll
      for (int d = 1; d < 64; d <<= 1) {
        float o = __shfl_up(gt, d);
        if (t >= d) gt += o;
      }
      Gar[t] = gt;
      gamv[t] = __expf(gt);
      barr[t] = bt;
      if (t == 63) { gcs[0] = gt; gcs[1] = __expf(gt); }
    }
    __syncthreads();

    // ---- phase 2: KK^T -> Mb, QK^T -> Nb; build Ktt ----
    {
      float4v aK[4] = {}, aQ[4] = {};
      const int arow = wv * 16 + l16;
      const int asw = (arow & 7) << 3;
#pragma unroll
      for (int kk = 0; kk < 4; kk++) {
        short8 av = *(const short8*)&Kb[arow][(kk * 32 + lg * 8) ^ asw];
        short8 aq = *(const short8*)&Qb[arow][(kk * 32 + lg * 8) ^ asw];
#pragma unroll
        for (int j = 0; j < 4; j++) {
          int brow = j * 16 + l16;
          short8 bv = *(const short8*)&Kb[brow][(kk * 32 + lg * 8) ^ ((brow & 7) << 3)];
          aK[j] = MFMA32(av, bv, aK[j]);
          aQ[j] = MFMA32(aq, bv, aQ[j]);
        }
      }
#pragma unroll
      for (int j = 0; j < 4; j++) {
#pragma unroll
        for (int reg = 0; reg < 4; reg++) {
          int tt = wv * 16 + lg * 4 + reg;
          int ii = j * 16 + l16;
          float sc = __expf(Gar[tt] - Gar[ii]);
          float mv = (ii < tt) ? aK[j][reg] * barr[tt] * sc : 0.f;
          float nv = (ii <= tt) ? aQ[j][reg] * sc : 0.f;
          Mb[tt][(ii ^ ((tt & 7) << 3))] = f2b(mv);
          Nb[tt][(ii ^ ((tt & 7) << 3))] = f2b(nv);
        }
      }
    }
    {
      int i = t >> 2, q4 = t & 3;
      float sc = __expf(gcs[0] - Gar[i]);
      int isw = (i & 7) << 3;
#pragma unroll
      for (int e8 = 0; e8 < 4; e8++) {
        int d0 = q4 * 32 + e8 * 8;
        short8 kv = *(const short8*)&Kb[i][d0 ^ isw];
#pragma unroll
        for (int e = 0; e < 8; e++) {
          int d = d0 + e;
          Ktt[d][i ^ ((d & 7) << 3)] = f2b(b2f((unsigned short)kv[e]) * sc);
        }
      }
    }
    __syncthreads();

    // ---- phase 3: P0t = S0 K^T; RHS -> Dbf; T-inverse -> Tb ----
    {
      float4v acc[4] = {};
      const int arow = wv * 16 + l16;  // v
      const int asw = (arow & 7) << 3;
#pragma unroll
      for (int kk = 0; kk < 4; kk++) {
        short8 av = *(const short8*)&Sb[arow][(kk * 32 + lg * 8) ^ asw];
#pragma unroll
        for (int j = 0; j < 4; j++) {
          int brow = j * 16 + l16;  // t
          short8 bv = *(const short8*)&Kb[brow][(kk * 32 + lg * 8) ^ ((brow & 7) << 3)];
          acc[j] = MFMA32(av, bv, acc[j]);
        }
      }
#pragma unroll
      for (int j = 0; j < 4; j++) {
#pragma unroll
        for (int reg = 0; reg < 4; reg++) {
          int v = wv * 16 + lg * 4 + reg;
          int tt = j * 16 + l16;
          float vtv = b2f(Vt[v][tt ^ ((v & 7) << 3)]);
          float val = barr[tt] * (vtv - gamv[tt] * acc[j][reg]);
          Dbf[v][tt ^ ((v & 7) << 3)] = f2b(val);
        }
      }
    }
    {
      // T-inverse of diagonal block wv (unit lower)
      float Lrow[16];
#pragma unroll
      for (int i = 0; i < 16; i++)
        Lrow[i] = b2f(Mb[wv * 16 + l16][((wv * 16 + i) ^ ((l16 & 7) << 3))]);
      float Tc[16];
#pragma unroll
      for (int i = 0; i < 16; i++) Tc[i] = (i == l16) ? 1.f : 0.f;
#pragma unroll
      for (int tt = 1; tt < 16; tt++) {
        float s = 0.f;
#pragma unroll
        for (int i = 0; i < 16; i++) {
          if (i < tt)
            s += __int_as_float(__builtin_amdgcn_readlane(__float_as_int(Lrow[i]), tt)) * Tc[i];
        }
        Tc[tt] = ((tt == l16) ? 1.f : 0.f) - s;
      }
      if (lane < 16) {
#pragma unroll
        for (int tt = 0; tt < 16; tt++) Tb[wv][tt][l16] = f2b(Tc[tt]);
      }
    }
    __syncthreads();

    // ---- phase 4: block forward substitution, D = (I+M)^{-1} RHS ----
    {
      short8 a = (short8)(short)0, bT = (short8)(short)0;
      const int arow = wv * 16 + l16;
      if (lg < 2) {
        a = *(const short8*)&Dbf[arow][((lg * 8) ^ ((arow & 7) << 3))];
        bT = *(const short8*)&Tb[0][l16][lg * 8];
      }
      float4v acc0 = {};
      acc0 = MFMA32(a, bT, acc0);
      __syncthreads();
#pragma unroll
      for (int reg = 0; reg < 4; reg++) {
        int v = wv * 16 + lg * 4 + reg;
        Dbf[v][(l16 ^ ((v & 7) << 3))] = f2b(acc0[reg]);
      }
    }
    __syncthreads();
#pragma unroll
    for (int s = 1; s < 4; s++) {
      float4v acc = {};
      const int arow = wv * 16 + l16;
      const int mrow = s * 16 + l16;
#pragma unroll
      for (int j = 0; j < 3; j++) {
        if (j < s) {
          short8 a = (short8)(short)0, bM = (short8)(short)0;
          if (lg < 2) {
            a  = *(const short8*)&Dbf[arow][((j * 16 + lg * 8) ^ ((arow & 7) << 3))];
            bM = *(const short8*)&Mb[mrow][((j * 16 + lg * 8) ^ ((mrow & 7) << 3))];
          }
          acc = MFMA32(a, bM, acc);
        }
      }
#pragma unroll
      for (int reg = 0; reg < 4; reg++) {
        int v = wv * 16 + lg * 4 + reg;
        float rt = b2f(Dbf[v][((s * 16 + l16) ^ ((v & 7) << 3))]);
        rtmp[v][l16] = f2b(rt - acc[reg]);
      }
      __syncthreads();
      short8 a2 = (short8)(short)0, bT = (short8)(short)0;
      if (lg < 2) {
        a2 = *(const short8*)&rtmp[wv * 16 + l16][lg * 8];
        bT = *(const short8*)&Tb[s][l16][lg * 8];
      }
      float4v acc2 = {};
      acc2 = MFMA32(a2, bT, acc2);
      __syncthreads();
#pragma unroll
      for (int reg = 0; reg < 4; reg++) {
        int v = wv * 16 + lg * 4 + reg;
        Dbf[v][((s * 16 + l16) ^ ((v & 7) << 3))] = f2b(acc2[reg]);
      }
      __syncthreads();
    }

    // ---- phase 5: O = diag(gam) Q S0^T + N D ----
    {
      float4v acc[4] = {};
      const int arow = wv * 16 + l16;  // t
      const int asw = (arow & 7) << 3;
#pragma unroll
      for (int kk = 0; kk < 4; kk++) {
        short8 aq = *(const short8*)&Qb[arow][(kk * 32 + lg * 8) ^ asw];
#pragma unroll
        for (int j = 0; j < 4; j++) {
          int brow = j * 16 + l16;  // v
          short8 bs = *(const short8*)&Sb[brow][(kk * 32 + lg * 8) ^ ((brow & 7) << 3)];
          acc[j] = MFMA32(aq, bs, acc[j]);
        }
      }
#pragma unroll
      for (int j = 0; j < 4; j++) {
#pragma unroll
        for (int reg = 0; reg < 4; reg++) {
          int tt = wv * 16 + lg * 4 + reg;
          acc[j][reg] *= gamv[tt];
        }
      }
#pragma unroll
      for (int kk = 0; kk < 2; kk++) {
        short8 an = *(const short8*)&Nb[arow][(kk * 32 + lg * 8) ^ asw];
#pragma unroll
        for (int j = 0; j < 4; j++) {
          int brow = j * 16 + l16;  // v
          short8 bd = *(const short8*)&Dbf[brow][(kk * 32 + lg * 8) ^ ((brow & 7) << 3)];
          acc[j] = MFMA32(an, bd, acc[j]);
        }
      }
      __syncthreads();  // Vt consumed; reuse as obuf
#pragma unroll
      for (int j = 0; j < 4; j++) {
#pragma unroll
        for (int reg = 0; reg < 4; reg++) {
          int tt = wv * 16 + lg * 4 + reg;
          int v = j * 16 + l16;
          Vt[tt][v ^ ((tt & 7) << 3)] = f2b(acc[j][reg]);
        }
      }
    }
    __syncthreads();
    {
      int tt = t >> 2, q4 = t & 3;
      int sw = (tt & 7) << 3;
      unsigned short* yg = y + (size_t)(bS + s0 + tt) * 4096 + h * 128 + half * 64 + q4 * 16;
      short8 o0 = *(const short8*)&Vt[tt][(q4 * 16) ^ sw];
      short8 o1 = *(const short8*)&Vt[tt][(q4 * 16 + 8) ^ sw];
      *(short8*)yg = o0;
      *(short8*)(yg + 8) = o1;
    }

    // ---- phase 6: state update S = gamC * S + D^T Ktt ----
    {
      float gC = gcs[1];
#pragma unroll
      for (int dt = 0; dt < 8; dt++)
#pragma unroll
        for (int reg = 0; reg < 4; reg++) accS[dt][reg] *= gC;
      const int arow = wv * 16 + l16;  // v
      const int asw = (arow & 7) << 3;
#pragma unroll
      for (int kk = 0; kk < 2; kk++) {
        short8 ad = *(const short8*)&Dbf[arow][(kk * 32 + lg * 8) ^ asw];
#pragma unroll
        for (int dt = 0; dt < 8; dt++) {
          int brow = dt * 16 + l16;  // d
          short8 bk = *(const short8*)&Ktt[brow][(kk * 32 + lg * 8) ^ ((brow & 7) << 3)];
          accS[dt] = MFMA32(ad, bk, accS[dt]);
        }
      }
      __syncthreads();
#pragma unroll
      for (int dt = 0; dt < 8; dt++) {
#pragma unroll
        for (int reg = 0; reg < 4; reg++) {
          int v = wv * 16 + lg * 4 + reg;
          int d = dt * 16 + l16;
          Sb[v][d ^ ((v & 7) << 3)] = f2b(accS[dt][reg]);
        }
      }
    }
    __syncthreads();
  }

  // final state writeout (fp32)
#pragma unroll
  for (int dt = 0; dt < 8; dt++) {
#pragma unroll
    for (int reg = 0; reg < 4; reg++) {
      int v = wv * 16 + lg * 4 + reg;
      int d = dt * 16 + l16;
      state_out[((size_t)((b * 32 + h) * 128 + half * 64 + v)) * 128 + d] = accS[dt][reg];
    }
  }
}

// ---- RMSNorm over DV * norm_w * silu(z) -> yn bf16 ----
__global__ __launch_bounds__(256)
void rms_silu(const unsigned short* __restrict__ y, const unsigned short* __restrict__ qkvz,
              const float* __restrict__ nw, unsigned short* __restrict__ yn) {
  int m = blockIdx.x;
  int t = threadIdx.x;
  int head = t >> 3, oct = t & 7;
  int vb = head * 128 + oct * 16;
  const unsigned short* yp = y + (size_t)m * 4096 + vb;
  float yy[16];
  short8 y0 = *(const short8*)yp, y1 = *(const short8*)(yp + 8);
#pragma unroll
  for (int e = 0; e < 8; e++) { yy[e] = b2f((unsigned short)y0[e]); yy[8 + e] = b2f((unsigned short)y1[e]); }
  float ss = 0.f;
#pragma unroll
  for (int e = 0; e < 16; e++) ss += yy[e] * yy[e];
  ss += __shfl_xor(ss, 1); ss += __shfl_xor(ss, 2); ss += __shfl_xor(ss, 4);
  float rinv = rsqrtf(ss * (1.f / 128.f) + 1e-6f);
  const unsigned short* zp = qkvz + (size_t)m * NP + 8192 + vb;
  short8 z0 = *(const short8*)zp, z1 = *(const short8*)(zp + 8);
  short8 o0, o1;
#pragma unroll
  for (int e = 0; e < 8; e++) {
    float z = b2f((unsigned short)z0[e]);
    float v = nw[oct * 16 + e] * yy[e] * rinv * (z / (1.f + expf(-z)));
    o0[e] = (short)f2b(v);
    z = b2f((unsigned short)z1[e]);
    v = nw[oct * 16 + 8 + e] * yy[8 + e] * rinv * (z / (1.f + expf(-z)));
    o1[e] = (short)f2b(v);
  }
  unsigned short* op = yn + (size_t)m * 4096 + vb;
  *(short8*)op = o0;
  *(short8*)(op + 8) = o1;
}

extern "C" void kernel_launch(void* const* d_in, const int* in_sizes, int n_in,
                              void* d_out, int out_size, void* d_ws, size_t ws_size,
                              hipStream_t stream) {
  if (ws_size < WS_NEED) return;  // guard: fail with clean absmax, not a fault

  const float* x     = (const float*)d_in[0];
  const float* Wqkv  = (const float*)d_in[1];
  const float* Wz    = (const float*)d_in[2];
  const float* Wa    = (const float*)d_in[3];
  const float* Wb    = (const float*)d_in[4];
  const float* convw = (const float*)d_in[5];
  const float* Alog  = (const float*)d_in[6];
  const float* dtb   = (const float*)d_in[7];
  const float* nw    = (const float*)d_in[8];
  const float* Wout  = (const float*)d_in[9];

  char* ws = (char*)d_ws;
  unsigned short* qkvz = (unsigned short*)(ws + OFF_QKVZ);
  unsigned short* xb   = (unsigned short*)(ws + OFF_XB);
  unsigned short* wcat = (unsigned short*)(ws + OFF_WCAT);
  unsigned short* qkvs = (unsigned short*)(ws + OFF_QKVS);
  unsigned short* ynb  = (unsigned short*)(ws + OFF_YN);
  unsigned short* wob  = (unsigned short*)(ws + OFF_WOB);
  float* gbuf          = (float*)(ws + OFF_G);
  float* bbuf          = (float*)(ws + OFF_BET);

  float* outp       = (float*)d_out;
  float* conv_state = outp + 8388608;             // B*S*H
  float* state      = outp + 8388608 + 131072;    // + B*CI*KW
  unsigned short* ybuf = (unsigned short*)d_out;  // y bf16 scratch over outp region

  castk<<<8192, 256, 0, stream>>>(x, xb, 2097152);
  prep_wcat<<<25088, 256, 0, stream>>>(Wqkv, Wz, Wa, Wb, wcat);

  // GEMM1: bn-major XCD chunks (each XCD keeps a B-col slab near-L2-resident)
  gemm_ring<256, true, unsigned short><<<784, 512, 0, stream>>>(xb, wcat, qkvz, 2048, 16, 49, NP);

  conv_silu_norm<<<256, 1024, 0, stream>>>(qkvz, convw, qkvs);
  conv_state_k<<<512, 256, 0, stream>>>(qkvz, conv_state);
  gb_kernel<<<1024, 256, 0, stream>>>(qkvz, Alog, dtb, gbuf, bbuf);

  scan_chunk<<<256, 256, 0, stream>>>(qkvs, gbuf, bbuf, ybuf, state);

  rms_silu<<<4096, 256, 0, stream>>>(ybuf, qkvz, nw, ynb);
  castk<<<8192, 256, 0, stream>>>(Wout, wob, 2097152);

  // GEMM2: BM=128 -> 256 blocks (all CUs busy), bm-major XCD chunks
  gemm_ring<128, false, float><<<256, 512, 0, stream>>>(ynb, wob, outp, 4096, 32, 8, 2048);
}

// Round 9
// 575.917 us; speedup vs baseline: 1.0400x; 1.0400x over previous
//
#include <hip/hip_runtime.h>
#include <cstdint>
#include <cstddef>

typedef __attribute__((ext_vector_type(8))) short short8;
typedef __attribute__((ext_vector_type(4))) short short4v;
typedef __attribute__((ext_vector_type(4))) float float4v;

#define DEV static __device__ __forceinline__

DEV float b2f(unsigned short u) { return __uint_as_float(((unsigned int)u) << 16); }
DEV unsigned short f2b(float f) {
  unsigned int u = __float_as_uint(f);
  u = (u + 0x7fffu + ((u >> 16) & 1u)) >> 16;
  return (unsigned short)u;
}

#define MFMA32(a, b, c) __builtin_amdgcn_mfma_f32_16x16x32_bf16(a, b, c, 0, 0, 0)

// ---- problem sizes ----
static constexpr int NP   = 12416;  // qkvz stride: 8192 qkv + 4096 z + 32 a + 32 b + 64 pad
static constexpr int NPAD = 12544;  // wcat rows padded to 49*256 for 256-tile GEMM

// ---- ws layout (bytes), lifetime-overlaid; peak ~162 MB ----
static constexpr size_t OFF_QKVZ = 0;
static constexpr size_t SZ_QKVZ  = (size_t)4096*NP*2;        // 101,711,872
static constexpr size_t OFF_XB   = SZ_QKVZ;
static constexpr size_t SZ_XB    = (size_t)4096*2048*2;      // 16,777,216
static constexpr size_t OFF_WCAT = OFF_XB + SZ_XB;
static constexpr size_t SZ_WCAT  = (size_t)NPAD*2048*2;      // 51,380,224
static constexpr size_t OFF_QKVS = OFF_XB;                   // overlays xb+wcat after GEMM1
static constexpr size_t SZ_QKVS  = (size_t)4096*8192*2;      // 67,108,864
static constexpr size_t OFF_G    = OFF_XB + SZ_QKVS;         // fits in gap before wcat end
static constexpr size_t OFF_BET  = OFF_G + (size_t)4096*32*4;
static constexpr size_t OFF_YN   = OFF_XB;                   // after scan
static constexpr size_t SZ_YN    = (size_t)4096*4096*2;
static constexpr size_t OFF_WOB  = OFF_YN + SZ_YN;
static constexpr size_t WS_NEED  = OFF_WCAT + SZ_WCAT;       // 169,869,312

// ---- helpers ----
DEV void gl16(const unsigned short* g, char* l) {
  __builtin_amdgcn_global_load_lds((const __attribute__((address_space(1))) unsigned int*)g,
                                   (__attribute__((address_space(3))) unsigned int*)l,
                                   16, 0, 0);
}

DEV void store_out(unsigned short* C, size_t off, float v) { C[off] = f2b(v); }
DEV void store_out(float* C, size_t off, float v)          { C[off] = v; }

// ---- generic cast fp32 -> bf16 (n multiple of 4) ----
__global__ void castk(const float* __restrict__ in, unsigned short* __restrict__ out, int n4) {
  int idx = blockIdx.x * 256 + threadIdx.x;
  if (idx >= n4) return;
  float4v v = ((const float4v*)in)[idx];
  short4v o;
  o[0] = (short)f2b(v[0]); o[1] = (short)f2b(v[1]);
  o[2] = (short)f2b(v[2]); o[3] = (short)f2b(v[3]);
  ((short4v*)out)[idx] = o;
}

// ---- build concatenated weight [12544][2048] bf16 ----
__global__ void prep_wcat(const float* __restrict__ Wqkv, const float* __restrict__ Wz,
                          const float* __restrict__ Wa, const float* __restrict__ Wb,
                          unsigned short* __restrict__ Wcat) {
  size_t e4 = (size_t)blockIdx.x * 256 + threadIdx.x;
  if (e4 >= (size_t)NPAD * 2048 / 4) return;
  size_t e = e4 * 4;
  int row = (int)(e >> 11);
  int col = (int)(e & 2047);
  float4v v;
  if (row < 8192)       v = *(const float4v*)&Wqkv[(size_t)row * 2048 + col];
  else if (row < 12288) v = *(const float4v*)&Wz[(size_t)(row - 8192) * 2048 + col];
  else if (row < 12320) v = *(const float4v*)&Wa[(size_t)(row - 12288) * 2048 + col];
  else if (row < 12352) v = *(const float4v*)&Wb[(size_t)(row - 12320) * 2048 + col];
  else                  v = (float4v){0.f, 0.f, 0.f, 0.f};
  short4v o;
  o[0] = (short)f2b(v[0]); o[1] = (short)f2b(v[1]);
  o[2] = (short)f2b(v[2]); o[3] = (short)f2b(v[3]);
  *(short4v*)&Wcat[e] = o;
}

// ========= BM x 256 ring-pipelined bf16 MFMA GEMM (BK=32, 4-slot ring) ======
// C[M][NC] = A[M][K] @ B[N][K]^T. 512 thr = 8 waves (2M x 4N at BM=256).
// Ring of 4 K-tile slots; counted vmcnt(2*TL) keeps 2 K-tiles of loads in
// flight across every barrier (never drains to 0 in the main loop).
// LDS rows are 64B (BK=32): column-slot c of row r stored at s = c^((r>>1)&3),
// giving each 16-lane group a 2-way-uniform bank tiling (free, m136); staged
// via linear global_load_lds dest + inverse-permuted global SOURCE column.
template <int BM, bool BNMAJOR, typename OutT>
__global__ __launch_bounds__(512, 2)
void gemm_ring(const unsigned short* __restrict__ A, const unsigned short* __restrict__ B,
               OutT* __restrict__ C, int K, int nbm, int nbn, int NC) {
  constexpr int MH   = BM / 128;          // 2 (BM=256) or 1 (BM=128)
  constexpr int AL   = BM / 128;          // gl16 rounds per A K-tile
  constexpr int BL   = 2;                 // gl16 rounds per B K-tile
  constexpr int TL   = AL + BL;           // loads per thread per K-tile
  constexpr int ASZ  = BM * 64;           // bytes: BM rows x 32 bf16
  constexpr int SLOT = ASZ + 16384;       // + B: 256 rows x 32 bf16
  __shared__ __align__(16) char sm[4 * SLOT];
  const int t = threadIdx.x;
  const int cpx = gridDim.x >> 3;
  int wg = blockIdx.x;
  wg = (wg & 7) * cpx + (wg >> 3);        // bijective XCD swizzle (grid % 8 == 0)
  const int bm = BNMAJOR ? (wg % nbm) : (wg / nbn);
  const int bn = BNMAJOR ? (wg / nbm) : (wg % nbn);

  const int wv = t >> 6, lane = t & 63;
  const int l16 = lane & 15, lg = lane >> 4;
  const int wm = (wv >> 2) * (BM / 2);
  const int wn = (wv & 3) * 64;
  // constant per-lane swizzled byte offset within a 64B row
  const int rsw = (lg ^ ((l16 >> 1) & 3)) << 4;

  size_t aoff[AL], boff[BL];
#pragma unroll
  for (int r = 0; r < AL; r++) {
    int L = r * 8192 + t * 16;
    int row = L >> 6;
    int c = ((L >> 4) & 3) ^ ((row >> 1) & 3);   // inverse-permuted source col-slot
    aoff[r] = (size_t)(bm * BM + row) * K + (c << 3);
  }
#pragma unroll
  for (int r = 0; r < BL; r++) {
    int L = r * 8192 + t * 16;
    int row = L >> 6;
    int c = ((L >> 4) & 3) ^ ((row >> 1) & 3);
    boff[r] = (size_t)(bn * 256 + row) * K + (c << 3);
  }

  float4v acc[MH * 4][4] = {};
  const int NKT = K >> 5;

#define STAGE(j)                                                              \
  do {                                                                        \
    const size_t ko = (size_t)(j) * 32;                                       \
    char* slot = sm + ((j) & 3) * SLOT;                                       \
    _Pragma("unroll") for (int r = 0; r < AL; r++)                            \
        gl16(A + aoff[r] + ko, slot + r * 8192 + t * 16);                     \
    _Pragma("unroll") for (int r = 0; r < BL; r++)                            \
        gl16(B + boff[r] + ko, slot + ASZ + r * 8192 + t * 16);               \
  } while (0)

#define COMPUTE(j)                                                            \
  do {                                                                        \
    char* ab = sm + ((j) & 3) * SLOT;                                         \
    char* bb = ab + ASZ;                                                      \
    short8 av[4], bv[4];                                                      \
    _Pragma("unroll") for (int nn = 0; nn < 4; nn++)                          \
        bv[nn] = *(const short8*)(bb + (wn + nn * 16 + l16) * 64 + rsw);      \
    _Pragma("unroll") for (int mi = 0; mi < 4; mi++)                          \
        av[mi] = *(const short8*)(ab + (wm + mi * 16 + l16) * 64 + rsw);      \
    __builtin_amdgcn_s_setprio(1);                                            \
    _Pragma("unroll") for (int mi = 0; mi < 4; mi++)                          \
    _Pragma("unroll") for (int nn = 0; nn < 4; nn++)                          \
        acc[mi][nn] = MFMA32(av[mi], bv[nn], acc[mi][nn]);                    \
    __builtin_amdgcn_s_setprio(0);                                            \
    if constexpr (MH == 2) {                                                  \
      _Pragma("unroll") for (int mi = 0; mi < 4; mi++)                        \
          av[mi] = *(const short8*)(ab + (wm + 64 + mi * 16 + l16) * 64 + rsw); \
      __builtin_amdgcn_s_setprio(1);                                          \
      _Pragma("unroll") for (int mi = 0; mi < 4; mi++)                        \
      _Pragma("unroll") for (int nn = 0; nn < 4; nn++)                        \
          acc[4 + mi][nn] = MFMA32(av[mi], bv[nn], acc[4 + mi][nn]);          \
      __builtin_amdgcn_s_setprio(0);                                          \
    }                                                                         \
  } while (0)

  // prologue: stage K-tiles 0..2; wait for K-tile 0 (2 tiles stay in flight)
  STAGE(0);
  STAGE(1);
  STAGE(2);
  asm volatile("s_waitcnt vmcnt(%0)" ::"n"(2 * TL) : "memory");
  __builtin_amdgcn_s_barrier();
  __builtin_amdgcn_sched_barrier(0);

  // main loop: counted vmcnt — never drains to 0
  for (int j = 0; j < NKT - 3; j++) {
    STAGE(j + 3);
    COMPUTE(j);
    asm volatile("s_waitcnt vmcnt(%0)" ::"n"(2 * TL) : "memory");
    __builtin_amdgcn_s_barrier();
    __builtin_amdgcn_sched_barrier(0);
  }
  // tail: last 3 K-tiles, full drain
  for (int j = NKT - 3; j < NKT; j++) {
    COMPUTE(j);
    asm volatile("s_waitcnt vmcnt(0)" ::: "memory");
    __builtin_amdgcn_s_barrier();
    __builtin_amdgcn_sched_barrier(0);
  }
#undef STAGE
#undef COMPUTE

  // epilogue
#pragma unroll
  for (int m = 0; m < MH * 4; m++) {
    int row0 = bm * BM + wm + m * 16 + lg * 4;
#pragma unroll
    for (int n = 0; n < 4; n++) {
      int col = bn * 256 + wn + n * 16 + l16;
      if (col < NC) {
#pragma unroll
        for (int rr = 0; rr < 4; rr++)
          store_out(C, (size_t)(row0 + rr) * NC + col, acc[m][n][rr]);
      }
    }
  }
}

// ---- conv(KW=4) + silu + q/k L2-norm, time-chunked (halo L1-reuse) ----
__global__ __launch_bounds__(1024)
void conv_silu_norm(const unsigned short* __restrict__ qkvz, const float* __restrict__ conv_w,
                    unsigned short* __restrict__ qkvs) {
  const int blk = blockIdx.x;
  const int b = blk >> 6;
  const int s0 = (blk & 63) << 4;
  const int t = threadIdx.x;
  const int c0 = t * 8;
  float w[8][4];
#pragma unroll
  for (int e = 0; e < 8; e++) {
    float4v wv = *(const float4v*)&conv_w[(c0 + e) * 4];
    w[e][0] = wv[0]; w[e][1] = wv[1]; w[e][2] = wv[2]; w[e][3] = wv[3];
  }
  const size_t base = (size_t)(b << 10) * NP + c0;
  const bool qk = c0 < 4096;
  const float qsc = (c0 < 2048) ? 0.08838834764831845f : 1.f;
#pragma unroll 1
  for (int i = 0; i < 16; i++) {
    const int s = s0 + i;
    float acc[8] = {0.f, 0.f, 0.f, 0.f, 0.f, 0.f, 0.f, 0.f};
#pragma unroll
    for (int j = 0; j < 4; j++) {
      const int sj = s - 3 + j;
      if (sj >= 0) {
        short8 v8 = *(const short8*)&qkvz[base + (size_t)sj * NP];
#pragma unroll
        for (int e = 0; e < 8; e++) acc[e] = fmaf(b2f((unsigned short)v8[e]), w[e][j], acc[e]);
      }
    }
    float out[8];
#pragma unroll
    for (int e = 0; e < 8; e++) { float xv = acc[e]; out[e] = xv * (1.f / (1.f + expf(-xv))); }
    if (qk) {
      float ss = 0.f;
#pragma unroll
      for (int e = 0; e < 8; e++) ss += out[e] * out[e];
      ss += __shfl_xor(ss, 1); ss += __shfl_xor(ss, 2);
      ss += __shfl_xor(ss, 4); ss += __shfl_xor(ss, 8);
      float sc = rsqrtf(ss + 1e-6f) * qsc;
#pragma unroll
      for (int e = 0; e < 8; e++) out[e] *= sc;
    }
    short8 o;
#pragma unroll
    for (int e = 0; e < 8; e++) o[e] = (short)f2b(out[e]);
    *(short8*)&qkvs[(size_t)((b << 10) + s) * 8192 + c0] = o;
  }
}

// ---- conv_state output: (B,CI,KW) fp32 from pre-conv qkv ----
__global__ void conv_state_k(const unsigned short* __restrict__ qkvz, float* __restrict__ cs) {
  int idx = blockIdx.x * 256 + threadIdx.x;  // < 131072 = 4*8192*4
  int b = idx >> 15;
  int rem = idx & 32767;
  int c = rem >> 2;
  int j = rem & 3;
  cs[idx] = b2f(qkvz[(size_t)(b * 1024 + 1020 + j) * NP + c]);
}

// ---- g / beta from a,b columns ----
__global__ void gb_kernel(const unsigned short* __restrict__ qkvz, const float* __restrict__ A_log,
                          const float* __restrict__ dt_bias, float* __restrict__ g,
                          float* __restrict__ bet) {
  int idx = blockIdx.x * 256 + threadIdx.x;  // < 4096*64
  int m = idx >> 6, n = idx & 63;
  if (n < 32) {
    float a = b2f(qkvz[(size_t)m * NP + 12288 + n]) + dt_bias[n];
    float sp = (a > 20.f) ? a : log1pf(expf(a));
    g[m * 32 + n] = -expf(A_log[n]) * sp;
  } else {
    int nn = n - 32;
    float bb = b2f(qkvz[(size_t)m * NP + 12320 + nn]);
    bet[m * 32 + nn] = 1.f / (1.f + expf(-bb));
  }
}

// ---- chunked delta-rule scan (UT transform), C=64, MFMA throughout ----
__global__ __launch_bounds__(256)
void scan_chunk(const unsigned short* __restrict__ qkvs, const float* __restrict__ g,
                const float* __restrict__ bet, unsigned short* __restrict__ y,
                float* __restrict__ state_out) {
  __shared__ __align__(16) unsigned short Kb[64][128];
  __shared__ __align__(16) unsigned short Qb[64][128];
  __shared__ __align__(16) unsigned short Sb[64][128];
  __shared__ __align__(16) unsigned short Ktt[128][64];
  __shared__ __align__(16) unsigned short Mb[64][64];
  __shared__ __align__(16) unsigned short Nb[64][64];
  __shared__ __align__(16) unsigned short Dbf[64][64];
  __shared__ __align__(16) unsigned short Vt[64][64];   // also reused as obuf
  __shared__ __align__(16) unsigned short Tb[4][16][16];
  __shared__ __align__(16) unsigned short rtmp[64][16];
  __shared__ float Gar[64];
  __shared__ float gamv[64];
  __shared__ float barr[64];
  __shared__ float gcs[2];

  const int bid = blockIdx.x;
  const int b = bid >> 6;
  const int h = (bid >> 1) & 31;
  const int half = bid & 1;
  const int hk = h >> 1;
  const int t = threadIdx.x;
  const int wv = t >> 6, lane = t & 63;
  const int l16 = lane & 15, lg = lane >> 4;
  const int bS = b << 10;

  float4v accS[8] = {};
  for (int idx = t; idx < 64 * 128; idx += 256) (&Sb[0][0])[idx] = 0;

  for (int ch = 0; ch < 16; ch++) {
    const int s0 = ch << 6;
    // ---- phase 1: stage Kb, Qb (swizzled via source permutation), Vt, g/beta ----
    {
#pragma unroll
      for (int rep = 0; rep < 4; rep++) {
        int rb = wv * 16 + rep * 4;
        int i = rb + (lane >> 4);
        int cg = (lane & 15) ^ (i & 7);
        const unsigned short* gk = qkvs + (size_t)(bS + s0 + i) * 8192 + 2048 + hk * 128 + cg * 8;
        gl16(gk, (char*)(&Kb[rb][0] + lane * 8));
        const unsigned short* gq = qkvs + (size_t)(bS + s0 + i) * 8192 + hk * 128 + cg * 8;
        gl16(gq, (char*)(&Qb[rb][0] + lane * 8));
      }
    }
    {
      int tt = t >> 2, q4 = t & 3;
      const unsigned short* gv = qkvs + (size_t)(bS + s0 + tt) * 8192 + 4096 + h * 128 + half * 64 + q4 * 16;
      short8 v0 = *(const short8*)gv;
      short8 v1 = *(const short8*)(gv + 8);
#pragma unroll
      for (int e = 0; e < 8; e++) {
        int v = q4 * 16 + e;
        Vt[v][tt ^ ((v & 7) << 3)] = (unsigned short)v0[e];
        v = q4 * 16 + 8 + e;
        Vt[v][tt ^ ((v & 7) << 3)] = (unsigned short)v1[e];
      }
    }
    if (t < 64) {
      float gt = g[(bS + s0 + t) * 32 + h];
      float bt = bet[(bS + s0 + t) * 32 + h];
#pragma unroll
      for (int d = 1; d < 64; d <<= 1) {
        float o = __shfl_up(gt, d);
        if (t >= d) gt += o;
      }
      Gar[t] = gt;
      gamv[t] = __expf(gt);
      barr[t] = bt;
      if (t == 63) { gcs[0] = gt; gcs[1] = __expf(gt); }
    }
    __syncthreads();

    // ---- phase 2: KK^T -> Mb, QK^T -> Nb; build Ktt ----
    {
      float4v aK[4] = {}, aQ[4] = {};
      const int arow = wv * 16 + l16;
      const int asw = (arow & 7) << 3;
#pragma unroll
      for (int kk = 0; kk < 4; kk++) {
        short8 av = *(const short8*)&Kb[arow][(kk * 32 + lg * 8) ^ asw];
        short8 aq = *(const short8*)&Qb[arow][(kk * 32 + lg * 8) ^ asw];
#pragma unroll
        for (int j = 0; j < 4; j++) {
          int brow = j * 16 + l16;
          short8 bv = *(const short8*)&Kb[brow][(kk * 32 + lg * 8) ^ ((brow & 7) << 3)];
          aK[j] = MFMA32(av, bv, aK[j]);
          aQ[j] = MFMA32(aq, bv, aQ[j]);
        }
      }
#pragma unroll
      for (int j = 0; j < 4; j++) {
#pragma unroll
        for (int reg = 0; reg < 4; reg++) {
          int tt = wv * 16 + lg * 4 + reg;
          int ii = j * 16 + l16;
          float sc = __expf(Gar[tt] - Gar[ii]);
          float mv = (ii < tt) ? aK[j][reg] * barr[tt] * sc : 0.f;
          float nv = (ii <= tt) ? aQ[j][reg] * sc : 0.f;
          Mb[tt][(ii ^ ((tt & 7) << 3))] = f2b(mv);
          Nb[tt][(ii ^ ((tt & 7) << 3))] = f2b(nv);
        }
      }
    }
    {
      int i = t >> 2, q4 = t & 3;
      float sc = __expf(gcs[0] - Gar[i]);
      int isw = (i & 7) << 3;
#pragma unroll
      for (int e8 = 0; e8 < 4; e8++) {
        int d0 = q4 * 32 + e8 * 8;
        short8 kv = *(const short8*)&Kb[i][d0 ^ isw];
#pragma unroll
        for (int e = 0; e < 8; e++) {
          int d = d0 + e;
          Ktt[d][i ^ ((d & 7) << 3)] = f2b(b2f((unsigned short)kv[e]) * sc);
        }
      }
    }
    __syncthreads();

    // ---- phase 3: P0t = S0 K^T; RHS -> Dbf; T-inverse -> Tb ----
    {
      float4v acc[4] = {};
      const int arow = wv * 16 + l16;  // v
      const int asw = (arow & 7) << 3;
#pragma unroll
      for (int kk = 0; kk < 4; kk++) {
        short8 av = *(const short8*)&Sb[arow][(kk * 32 + lg * 8) ^ asw];
#pragma unroll
        for (int j = 0; j < 4; j++) {
          int brow = j * 16 + l16;  // t
          short8 bv = *(const short8*)&Kb[brow][(kk * 32 + lg * 8) ^ ((brow & 7) << 3)];
          acc[j] = MFMA32(av, bv, acc[j]);
        }
      }
#pragma unroll
      for (int j = 0; j < 4; j++) {
#pragma unroll
        for (int reg = 0; reg < 4; reg++) {
          int v = wv * 16 + lg * 4 + reg;
          int tt = j * 16 + l16;
          float vtv = b2f(Vt[v][tt ^ ((v & 7) << 3)]);
          float val = barr[tt] * (vtv - gamv[tt] * acc[j][reg]);
          Dbf[v][tt ^ ((v & 7) << 3)] = f2b(val);
        }
      }
    }
    {
      // T-inverse of diagonal block wv (unit lower)
      float Lrow[16];
#pragma unroll
      for (int i = 0; i < 16; i++)
        Lrow[i] = b2f(Mb[wv * 16 + l16][((wv * 16 + i) ^ ((l16 & 7) << 3))]);
      float Tc[16];
#pragma unroll
      for (int i = 0; i < 16; i++) Tc[i] = (i == l16) ? 1.f : 0.f;
#pragma unroll
      for (int tt = 1; tt < 16; tt++) {
        float s = 0.f;
#pragma unroll
        for (int i = 0; i < 16; i++) {
          if (i < tt)
            s += __int_as_float(__builtin_amdgcn_readlane(__float_as_int(Lrow[i]), tt)) * Tc[i];
        }
        Tc[tt] = ((tt == l16) ? 1.f : 0.f) - s;
      }
      if (lane < 16) {
#pragma unroll
        for (int tt = 0; tt < 16; tt++) Tb[wv][tt][l16] = f2b(Tc[tt]);
      }
    }
    __syncthreads();

    // ---- phase 4: block forward substitution, D = (I+M)^{-1} RHS ----
    {
      short8 a = (short8)(short)0, bT = (short8)(short)0;
      const int arow = wv * 16 + l16;
      if (lg < 2) {
        a = *(const short8*)&Dbf[arow][((lg * 8) ^ ((arow & 7) << 3))];
        bT = *(const short8*)&Tb[0][l16][lg * 8];
      }
      float4v acc0 = {};
      acc0 = MFMA32(a, bT, acc0);
      __syncthreads();
#pragma unroll
      for (int reg = 0; reg < 4; reg++) {
        int v = wv * 16 + lg * 4 + reg;
        Dbf[v][(l16 ^ ((v & 7) << 3))] = f2b(acc0[reg]);
      }
    }
    __syncthreads();
#pragma unroll
    for (int s = 1; s < 4; s++) {
      float4v acc = {};
      const int arow = wv * 16 + l16;
      const int mrow = s * 16 + l16;
#pragma unroll
      for (int j = 0; j < 3; j++) {
        if (j < s) {
          short8 a = (short8)(short)0, bM = (short8)(short)0;
          if (lg < 2) {
            a  = *(const short8*)&Dbf[arow][((j * 16 + lg * 8) ^ ((arow & 7) << 3))];
            bM = *(const short8*)&Mb[mrow][((j * 16 + lg * 8) ^ ((mrow & 7) << 3))];
          }
          acc = MFMA32(a, bM, acc);
        }
      }
#pragma unroll
      for (int reg = 0; reg < 4; reg++) {
        int v = wv * 16 + lg * 4 + reg;
        float rt = b2f(Dbf[v][((s * 16 + l16) ^ ((v & 7) << 3))]);
        rtmp[v][l16] = f2b(rt - acc[reg]);
      }
      __syncthreads();
      short8 a2 = (short8)(short)0, bT = (short8)(short)0;
      if (lg < 2) {
        a2 = *(const short8*)&rtmp[wv * 16 + l16][lg * 8];
        bT = *(const short8*)&Tb[s][l16][lg * 8];
      }
      float4v acc2 = {};
      acc2 = MFMA32(a2, bT, acc2);
      __syncthreads();
#pragma unroll
      for (int reg = 0; reg < 4; reg++) {
        int v = wv * 16 + lg * 4 + reg;
        Dbf[v][((s * 16 + l16) ^ ((v & 7) << 3))] = f2b(acc2[reg]);
      }
      __syncthreads();
    }

    // ---- phase 5: O = diag(gam) Q S0^T + N D ----
    {
      float4v acc[4] = {};
      const int arow = wv * 16 + l16;  // t
      const int asw = (arow & 7) << 3;
#pragma unroll
      for (int kk = 0; kk < 4; kk++) {
        short8 aq = *(const short8*)&Qb[arow][(kk * 32 + lg * 8) ^ asw];
#pragma unroll
        for (int j = 0; j < 4; j++) {
          int brow = j * 16 + l16;  // v
          short8 bs = *(const short8*)&Sb[brow][(kk * 32 + lg * 8) ^ ((brow & 7) << 3)];
          acc[j] = MFMA32(aq, bs, acc[j]);
        }
      }
#pragma unroll
      for (int j = 0; j < 4; j++) {
#pragma unroll
        for (int reg = 0; reg < 4; reg++) {
          int tt = wv * 16 + lg * 4 + reg;
          acc[j][reg] *= gamv[tt];
        }
      }
#pragma unroll
      for (int kk = 0; kk < 2; kk++) {
        short8 an = *(const short8*)&Nb[arow][(kk * 32 + lg * 8) ^ asw];
#pragma unroll
        for (int j = 0; j < 4; j++) {
          int brow = j * 16 + l16;  // v
          short8 bd = *(const short8*)&Dbf[brow][(kk * 32 + lg * 8) ^ ((brow & 7) << 3)];
          acc[j] = MFMA32(an, bd, acc[j]);
        }
      }
      __syncthreads();  // Vt consumed; reuse as obuf
#pragma unroll
      for (int j = 0; j < 4; j++) {
#pragma unroll
        for (int reg = 0; reg < 4; reg++) {
          int tt = wv * 16 + lg * 4 + reg;
          int v = j * 16 + l16;
          Vt[tt][v ^ ((tt & 7) << 3)] = f2b(acc[j][reg]);
        }
      }
    }
    __syncthreads();
    {
      int tt = t >> 2, q4 = t & 3;
      int sw = (tt & 7) << 3;
      unsigned short* yg = y + (size_t)(bS + s0 + tt) * 4096 + h * 128 + half * 64 + q4 * 16;
      short8 o0 = *(const short8*)&Vt[tt][(q4 * 16) ^ sw];
      short8 o1 = *(const short8*)&Vt[tt][(q4 * 16 + 8) ^ sw];
      *(short8*)yg = o0;
      *(short8*)(yg + 8) = o1;
    }

    // ---- phase 6: state update S = gamC * S + D^T Ktt ----
    {
      float gC = gcs[1];
#pragma unroll
      for (int dt = 0; dt < 8; dt++)
#pragma unroll
        for (int reg = 0; reg < 4; reg++) accS[dt][reg] *= gC;
      const int arow = wv * 16 + l16;  // v
      const int asw = (arow & 7) << 3;
#pragma unroll
      for (int kk = 0; kk < 2; kk++) {
        short8 ad = *(const short8*)&Dbf[arow][(kk * 32 + lg * 8) ^ asw];
#pragma unroll
        for (int dt = 0; dt < 8; dt++) {
          int brow = dt * 16 + l16;  // d
          short8 bk = *(const short8*)&Ktt[brow][(kk * 32 + lg * 8) ^ ((brow & 7) << 3)];
          accS[dt] = MFMA32(ad, bk, accS[dt]);
        }
      }
      __syncthreads();
#pragma unroll
      for (int dt = 0; dt < 8; dt++) {
#pragma unroll
        for (int reg = 0; reg < 4; reg++) {
          int v = wv * 16 + lg * 4 + reg;
          int d = dt * 16 + l16;
          Sb[v][d ^ ((v & 7) << 3)] = f2b(accS[dt][reg]);
        }
      }
    }
    __syncthreads();
  }

  // final state writeout (fp32)
#pragma unroll
  for (int dt = 0; dt < 8; dt++) {
#pragma unroll
    for (int reg = 0; reg < 4; reg++) {
      int v = wv * 16 + lg * 4 + reg;
      int d = dt * 16 + l16;
      state_out[((size_t)((b * 32 + h) * 128 + half * 64 + v)) * 128 + d] = accS[dt][reg];
    }
  }
}

// ---- RMSNorm over DV * norm_w * silu(z) -> yn bf16 ----
__global__ __launch_bounds__(256)
void rms_silu(const unsigned short* __restrict__ y, const unsigned short* __restrict__ qkvz,
              const float* __restrict__ nw, unsigned short* __restrict__ yn) {
  int m = blockIdx.x;
  int t = threadIdx.x;
  int head = t >> 3, oct = t & 7;
  int vb = head * 128 + oct * 16;
  const unsigned short* yp = y + (size_t)m * 4096 + vb;
  float yy[16];
  short8 y0 = *(const short8*)yp, y1 = *(const short8*)(yp + 8);
#pragma unroll
  for (int e = 0; e < 8; e++) { yy[e] = b2f((unsigned short)y0[e]); yy[8 + e] = b2f((unsigned short)y1[e]); }
  float ss = 0.f;
#pragma unroll
  for (int e = 0; e < 16; e++) ss += yy[e] * yy[e];
  ss += __shfl_xor(ss, 1); ss += __shfl_xor(ss, 2); ss += __shfl_xor(ss, 4);
  float rinv = rsqrtf(ss * (1.f / 128.f) + 1e-6f);
  const unsigned short* zp = qkvz + (size_t)m * NP + 8192 + vb;
  short8 z0 = *(const short8*)zp, z1 = *(const short8*)(zp + 8);
  short8 o0, o1;
#pragma unroll
  for (int e = 0; e < 8; e++) {
    float z = b2f((unsigned short)z0[e]);
    float v = nw[oct * 16 + e] * yy[e] * rinv * (z / (1.f + expf(-z)));
    o0[e] = (short)f2b(v);
    z = b2f((unsigned short)z1[e]);
    v = nw[oct * 16 + 8 + e] * yy[8 + e] * rinv * (z / (1.f + expf(-z)));
    o1[e] = (short)f2b(v);
  }
  unsigned short* op = yn + (size_t)m * 4096 + vb;
  *(short8*)op = o0;
  *(short8*)(op + 8) = o1;
}

extern "C" void kernel_launch(void* const* d_in, const int* in_sizes, int n_in,
                              void* d_out, int out_size, void* d_ws, size_t ws_size,
                              hipStream_t stream) {
  if (ws_size < WS_NEED) return;  // guard: fail with clean absmax, not a fault

  const float* x     = (const float*)d_in[0];
  const float* Wqkv  = (const float*)d_in[1];
  const float* Wz    = (const float*)d_in[2];
  const float* Wa    = (const float*)d_in[3];
  const float* Wb    = (const float*)d_in[4];
  const float* convw = (const float*)d_in[5];
  const float* Alog  = (const float*)d_in[6];
  const float* dtb   = (const float*)d_in[7];
  const float* nw    = (const float*)d_in[8];
  const float* Wout  = (const float*)d_in[9];

  char* ws = (char*)d_ws;
  unsigned short* qkvz = (unsigned short*)(ws + OFF_QKVZ);
  unsigned short* xb   = (unsigned short*)(ws + OFF_XB);
  unsigned short* wcat = (unsigned short*)(ws + OFF_WCAT);
  unsigned short* qkvs = (unsigned short*)(ws + OFF_QKVS);
  unsigned short* ynb  = (unsigned short*)(ws + OFF_YN);
  unsigned short* wob  = (unsigned short*)(ws + OFF_WOB);
  float* gbuf          = (float*)(ws + OFF_G);
  float* bbuf          = (float*)(ws + OFF_BET);

  float* outp       = (float*)d_out;
  float* conv_state = outp + 8388608;             // B*S*H
  float* state      = outp + 8388608 + 131072;    // + B*CI*KW
  unsigned short* ybuf = (unsigned short*)d_out;  // y bf16 scratch over outp region

  castk<<<8192, 256, 0, stream>>>(x, xb, 2097152);
  prep_wcat<<<25088, 256, 0, stream>>>(Wqkv, Wz, Wa, Wb, wcat);

  // GEMM1: bn-major XCD chunks (each XCD keeps a B-col slab near-L2-resident)
  gemm_ring<256, true, unsigned short><<<784, 512, 0, stream>>>(xb, wcat, qkvz, 2048, 16, 49, NP);

  conv_silu_norm<<<256, 1024, 0, stream>>>(qkvz, convw, qkvs);
  conv_state_k<<<512, 256, 0, stream>>>(qkvz, conv_state);
  gb_kernel<<<1024, 256, 0, stream>>>(qkvz, Alog, dtb, gbuf, bbuf);

  scan_chunk<<<256, 256, 0, stream>>>(qkvs, gbuf, bbuf, ybuf, state);

  rms_silu<<<4096, 256, 0, stream>>>(ybuf, qkvz, nw, ynb);
  castk<<<8192, 256, 0, stream>>>(Wout, wob, 2097152);

  // GEMM2: BM=128 -> 256 blocks (all CUs busy), bm-major XCD chunks
  gemm_ring<128, false, float><<<256, 512, 0, stream>>>(ynb, wob, outp, 4096, 32, 8, 2048);
}

// Round 10
// 574.160 us; speedup vs baseline: 1.0432x; 1.0031x over previous
//
#include <hip/hip_runtime.h>
#include <cstdint>
#include <cstddef>

typedef __attribute__((ext_vector_type(8))) short short8;
typedef __attribute__((ext_vector_type(4))) short short4v;
typedef __attribute__((ext_vector_type(4))) float float4v;

#define DEV static __device__ __forceinline__

DEV float b2f(unsigned short u) { return __uint_as_float(((unsigned int)u) << 16); }
DEV unsigned short f2b(float f) {
  unsigned int u = __float_as_uint(f);
  u = (u + 0x7fffu + ((u >> 16) & 1u)) >> 16;
  return (unsigned short)u;
}

#define MFMA32(a, b, c) __builtin_amdgcn_mfma_f32_16x16x32_bf16(a, b, c, 0, 0, 0)

// ---- problem sizes ----
static constexpr int NP   = 12416;  // qkvz stride: 8192 qkv + 4096 z + 32 a + 32 b + 64 pad
static constexpr int NPAD = 12544;  // wcat rows padded to 49*256 for 256-tile GEMM

// ---- ws layout (bytes), lifetime-overlaid; peak ~162 MB ----
static constexpr size_t OFF_QKVZ = 0;
static constexpr size_t SZ_QKVZ  = (size_t)4096*NP*2;        // 101,711,872
static constexpr size_t OFF_XB   = SZ_QKVZ;
static constexpr size_t SZ_XB    = (size_t)4096*2048*2;      // 16,777,216
static constexpr size_t OFF_WCAT = OFF_XB + SZ_XB;
static constexpr size_t SZ_WCAT  = (size_t)NPAD*2048*2;      // 51,380,224
static constexpr size_t OFF_QKVS = OFF_XB;                   // overlays xb+wcat after GEMM1
static constexpr size_t SZ_QKVS  = (size_t)4096*8192*2;      // 67,108,864
static constexpr size_t OFF_G    = OFF_XB + SZ_QKVS;         // fits in gap before wcat end
static constexpr size_t OFF_BET  = OFF_G + (size_t)4096*32*4;
static constexpr size_t OFF_YN   = OFF_XB;                   // after scan
static constexpr size_t SZ_YN    = (size_t)4096*4096*2;
static constexpr size_t OFF_WOB  = OFF_YN + SZ_YN;
static constexpr size_t WS_NEED  = OFF_WCAT + SZ_WCAT;       // 169,869,312

// ---- helpers ----
DEV void gl16(const unsigned short* g, char* l) {
  __builtin_amdgcn_global_load_lds((const __attribute__((address_space(1))) unsigned int*)g,
                                   (__attribute__((address_space(3))) unsigned int*)l,
                                   16, 0, 0);
}

DEV void store_out(unsigned short* C, size_t off, float v) { C[off] = f2b(v); }
DEV void store_out(float* C, size_t off, float v)          { C[off] = v; }

// ---- generic cast fp32 -> bf16 (n multiple of 4) ----
__global__ void castk(const float* __restrict__ in, unsigned short* __restrict__ out, int n4) {
  int idx = blockIdx.x * 256 + threadIdx.x;
  if (idx >= n4) return;
  float4v v = ((const float4v*)in)[idx];
  short4v o;
  o[0] = (short)f2b(v[0]); o[1] = (short)f2b(v[1]);
  o[2] = (short)f2b(v[2]); o[3] = (short)f2b(v[3]);
  ((short4v*)out)[idx] = o;
}

// ---- build concatenated weight [12544][2048] bf16 ----
__global__ void prep_wcat(const float* __restrict__ Wqkv, const float* __restrict__ Wz,
                          const float* __restrict__ Wa, const float* __restrict__ Wb,
                          unsigned short* __restrict__ Wcat) {
  size_t e4 = (size_t)blockIdx.x * 256 + threadIdx.x;
  if (e4 >= (size_t)NPAD * 2048 / 4) return;
  size_t e = e4 * 4;
  int row = (int)(e >> 11);
  int col = (int)(e & 2047);
  float4v v;
  if (row < 8192)       v = *(const float4v*)&Wqkv[(size_t)row * 2048 + col];
  else if (row < 12288) v = *(const float4v*)&Wz[(size_t)(row - 8192) * 2048 + col];
  else if (row < 12320) v = *(const float4v*)&Wa[(size_t)(row - 12288) * 2048 + col];
  else if (row < 12352) v = *(const float4v*)&Wb[(size_t)(row - 12320) * 2048 + col];
  else                  v = (float4v){0.f, 0.f, 0.f, 0.f};
  short4v o;
  o[0] = (short)f2b(v[0]); o[1] = (short)f2b(v[1]);
  o[2] = (short)f2b(v[2]); o[3] = (short)f2b(v[3]);
  *(short4v*)&Wcat[e] = o;
}

// ==== BM x 256 ring-pipelined bf16 MFMA GEMM, register-frag double-buffer ===
// Ring of 4 K-tile slots (BK=32). Per body j: stage K-tile j+3; ds_read A-hi(j)
// + ALL frags of j+1 into the spare register set; MFMA clusters run on the
// set loaded LAST iteration -> DS pipe serves next-frags while MFMA pipe runs
// current (per-wave ILP, no extra barriers). vmcnt(TL) counted at the barrier
// (1 stage in flight); swizzle: 64B rows with slot s = c ^ ((r>>1)&3).
template <int BM, bool BNMAJOR, typename OutT>
__global__ __launch_bounds__(512, 2)
void gemm_pipe(const unsigned short* __restrict__ A, const unsigned short* __restrict__ B,
               OutT* __restrict__ C, int K, int nbm, int nbn, int NC) {
  constexpr int MH   = BM / 128;          // 2 (BM=256) or 1 (BM=128)
  constexpr int AL   = BM / 128;          // gl16 rounds per A K-tile
  constexpr int BL   = 2;                 // gl16 rounds per B K-tile
  constexpr int TL   = AL + BL;           // loads per thread per K-tile
  constexpr int ASZ  = BM * 64;           // bytes: BM rows x 32 bf16
  constexpr int SLOT = ASZ + 16384;       // + B: 256 rows x 32 bf16
  __shared__ __align__(16) char sm[4 * SLOT];
  const int t = threadIdx.x;
  const int cpx = gridDim.x >> 3;
  int wg = blockIdx.x;
  wg = (wg & 7) * cpx + (wg >> 3);        // bijective XCD swizzle (grid % 8 == 0)
  const int bm = BNMAJOR ? (wg % nbm) : (wg / nbn);
  const int bn = BNMAJOR ? (wg / nbm) : (wg % nbn);

  const int wv = t >> 6, lane = t & 63;
  const int l16 = lane & 15, lg = lane >> 4;
  const int wm = (wv >> 2) * (BM / 2);
  const int wn = (wv & 3) * 64;
  const int rsw = (lg ^ ((l16 >> 1) & 3)) << 4;  // swizzled byte slot in 64B row

  size_t aoff[AL], boff[BL];
#pragma unroll
  for (int r = 0; r < AL; r++) {
    int L = r * 8192 + t * 16;
    int row = L >> 6;
    int c = ((L >> 4) & 3) ^ ((row >> 1) & 3);   // inverse-permuted source col-slot
    aoff[r] = (size_t)(bm * BM + row) * K + (c << 3);
  }
#pragma unroll
  for (int r = 0; r < BL; r++) {
    int L = r * 8192 + t * 16;
    int row = L >> 6;
    int c = ((L >> 4) & 3) ^ ((row >> 1) & 3);
    boff[r] = (size_t)(bn * 256 + row) * K + (c << 3);
  }

  float4v acc[MH * 4][4] = {};
  const int NKT = K >> 5;

#define STAGEK(J)                                                             \
  do {                                                                        \
    const size_t ko = (size_t)(J) * 32;                                       \
    char* slot = sm + ((J) & 3) * SLOT;                                       \
    _Pragma("unroll") for (int r = 0; r < AL; r++)                            \
        gl16(A + aoff[r] + ko, slot + r * 8192 + t * 16);                     \
    _Pragma("unroll") for (int r = 0; r < BL; r++)                            \
        gl16(B + boff[r] + ko, slot + ASZ + r * 8192 + t * 16);               \
  } while (0)

#define PREF(J, bvX, alX)                                                     \
  do {                                                                        \
    char* ab_ = sm + ((J) & 3) * SLOT;                                        \
    char* bb_ = ab_ + ASZ;                                                    \
    _Pragma("unroll") for (int nn = 0; nn < 4; nn++)                          \
        bvX[nn] = *(const short8*)(bb_ + (wn + nn * 16 + l16) * 64 + rsw);    \
    _Pragma("unroll") for (int mi = 0; mi < 4; mi++)                          \
        alX[mi] = *(const short8*)(ab_ + (wm + mi * 16 + l16) * 64 + rsw);    \
  } while (0)

#define BODY(J, bvC, alC, bvN, alN, DOSTAGE, PF, COUNTED)                     \
  do {                                                                        \
    if (DOSTAGE) STAGEK((J) + 3);                                             \
    short8 ah[4];                                                             \
    if constexpr (MH == 2) {                                                  \
      char* ab_ = sm + ((J) & 3) * SLOT;                                      \
      _Pragma("unroll") for (int mi = 0; mi < 4; mi++)                        \
          ah[mi] = *(const short8*)(ab_ + (wm + 64 + mi * 16 + l16) * 64 + rsw); \
    }                                                                         \
    if (PF) PREF((J) + 1, bvN, alN);                                          \
    __builtin_amdgcn_sched_barrier(0);  /* pin reads above MFMAs */           \
    __builtin_amdgcn_s_setprio(1);                                            \
    _Pragma("unroll") for (int mi = 0; mi < 4; mi++)                          \
    _Pragma("unroll") for (int nn = 0; nn < 4; nn++)                          \
        acc[mi][nn] = MFMA32(alC[mi], bvC[nn], acc[mi][nn]);                  \
    __builtin_amdgcn_s_setprio(0);                                            \
    if constexpr (MH == 2) {                                                  \
      __builtin_amdgcn_sched_barrier(0);                                      \
      __builtin_amdgcn_s_setprio(1);                                          \
      _Pragma("unroll") for (int mi = 0; mi < 4; mi++)                        \
      _Pragma("unroll") for (int nn = 0; nn < 4; nn++)                        \
          acc[4 + mi][nn] = MFMA32(ah[mi], bvC[nn], acc[4 + mi][nn]);         \
      __builtin_amdgcn_s_setprio(0);                                          \
    }                                                                         \
    if (COUNTED) { asm volatile("s_waitcnt vmcnt(%0)" ::"n"(TL) : "memory"); }\
    else         { asm volatile("s_waitcnt vmcnt(0)" ::: "memory"); }         \
    __builtin_amdgcn_s_barrier();                                             \
    __builtin_amdgcn_sched_barrier(0);                                        \
  } while (0)

  // prologue: stage 0..2; ensure slots 0,1 landed (1 stage may stay in flight)
  STAGEK(0);
  STAGEK(1);
  STAGEK(2);
  asm volatile("s_waitcnt vmcnt(%0)" ::"n"(TL) : "memory");
  __builtin_amdgcn_s_barrier();
  short8 bvP[4], alP[4], bvQ[4], alQ[4];
  PREF(0, bvP, alP);

  // main loop, unrolled x2 for static P/Q register sets (NKT is even)
  for (int j = 0; j < NKT - 4; j += 2) {
    BODY(j,     bvP, alP, bvQ, alQ, true, true, true);
    BODY(j + 1, bvQ, alQ, bvP, alP, true, true, true);
  }
  BODY(NKT - 4, bvP, alP, bvQ, alQ, true,  true,  true);
  BODY(NKT - 3, bvQ, alQ, bvP, alP, false, true,  false);
  BODY(NKT - 2, bvP, alP, bvQ, alQ, false, true,  false);
  BODY(NKT - 1, bvQ, alQ, bvP, alP, false, false, false);
#undef STAGEK
#undef PREF
#undef BODY

  // epilogue
#pragma unroll
  for (int m = 0; m < MH * 4; m++) {
    int row0 = bm * BM + wm + m * 16 + lg * 4;
#pragma unroll
    for (int n = 0; n < 4; n++) {
      int col = bn * 256 + wn + n * 16 + l16;
      if (col < NC) {
#pragma unroll
        for (int rr = 0; rr < 4; rr++)
          store_out(C, (size_t)(row0 + rr) * NC + col, acc[m][n][rr]);
      }
    }
  }
}

// ---- conv(KW=4) + silu + q/k L2-norm, time-chunked (halo L1-reuse) ----
__global__ __launch_bounds__(1024)
void conv_silu_norm(const unsigned short* __restrict__ qkvz, const float* __restrict__ conv_w,
                    unsigned short* __restrict__ qkvs) {
  const int blk = blockIdx.x;
  const int b = blk >> 6;
  const int s0 = (blk & 63) << 4;
  const int t = threadIdx.x;
  const int c0 = t * 8;
  float w[8][4];
#pragma unroll
  for (int e = 0; e < 8; e++) {
    float4v wv = *(const float4v*)&conv_w[(c0 + e) * 4];
    w[e][0] = wv[0]; w[e][1] = wv[1]; w[e][2] = wv[2]; w[e][3] = wv[3];
  }
  const size_t base = (size_t)(b << 10) * NP + c0;
  const bool qk = c0 < 4096;
  const float qsc = (c0 < 2048) ? 0.08838834764831845f : 1.f;
#pragma unroll 1
  for (int i = 0; i < 16; i++) {
    const int s = s0 + i;
    float acc[8] = {0.f, 0.f, 0.f, 0.f, 0.f, 0.f, 0.f, 0.f};
#pragma unroll
    for (int j = 0; j < 4; j++) {
      const int sj = s - 3 + j;
      if (sj >= 0) {
        short8 v8 = *(const short8*)&qkvz[base + (size_t)sj * NP];
#pragma unroll
        for (int e = 0; e < 8; e++) acc[e] = fmaf(b2f((unsigned short)v8[e]), w[e][j], acc[e]);
      }
    }
    float out[8];
#pragma unroll
    for (int e = 0; e < 8; e++) { float xv = acc[e]; out[e] = xv * (1.f / (1.f + expf(-xv))); }
    if (qk) {
      float ss = 0.f;
#pragma unroll
      for (int e = 0; e < 8; e++) ss += out[e] * out[e];
      ss += __shfl_xor(ss, 1); ss += __shfl_xor(ss, 2);
      ss += __shfl_xor(ss, 4); ss += __shfl_xor(ss, 8);
      float sc = rsqrtf(ss + 1e-6f) * qsc;
#pragma unroll
      for (int e = 0; e < 8; e++) out[e] *= sc;
    }
    short8 o;
#pragma unroll
    for (int e = 0; e < 8; e++) o[e] = (short)f2b(out[e]);
    *(short8*)&qkvs[(size_t)((b << 10) + s) * 8192 + c0] = o;
  }
}

// ---- conv_state output: (B,CI,KW) fp32 from pre-conv qkv ----
__global__ void conv_state_k(const unsigned short* __restrict__ qkvz, float* __restrict__ cs) {
  int idx = blockIdx.x * 256 + threadIdx.x;  // < 131072 = 4*8192*4
  int b = idx >> 15;
  int rem = idx & 32767;
  int c = rem >> 2;
  int j = rem & 3;
  cs[idx] = b2f(qkvz[(size_t)(b * 1024 + 1020 + j) * NP + c]);
}

// ---- g / beta from a,b columns ----
__global__ void gb_kernel(const unsigned short* __restrict__ qkvz, const float* __restrict__ A_log,
                          const float* __restrict__ dt_bias, float* __restrict__ g,
                          float* __restrict__ bet) {
  int idx = blockIdx.x * 256 + threadIdx.x;  // < 4096*64
  int m = idx >> 6, n = idx & 63;
  if (n < 32) {
    float a = b2f(qkvz[(size_t)m * NP + 12288 + n]) + dt_bias[n];
    float sp = (a > 20.f) ? a : log1pf(expf(a));
    g[m * 32 + n] = -expf(A_log[n]) * sp;
  } else {
    int nn = n - 32;
    float bb = b2f(qkvz[(size_t)m * NP + 12320 + nn]);
    bet[m * 32 + nn] = 1.f / (1.f + expf(-bb));
  }
}

// ---- chunked delta-rule scan (UT transform), C=64, MFMA throughout ----
__global__ __launch_bounds__(256)
void scan_chunk(const unsigned short* __restrict__ qkvs, const float* __restrict__ g,
                const float* __restrict__ bet, unsigned short* __restrict__ y,
                float* __restrict__ state_out) {
  __shared__ __align__(16) unsigned short Kb[64][128];
  __shared__ __align__(16) unsigned short Qb[64][128];
  __shared__ __align__(16) unsigned short Sb[64][128];
  __shared__ __align__(16) unsigned short Ktt[128][64];
  __shared__ __align__(16) unsigned short Mb[64][64];
  __shared__ __align__(16) unsigned short Nb[64][64];
  __shared__ __align__(16) unsigned short Dbf[64][64];
  __shared__ __align__(16) unsigned short Vt[64][64];   // also reused as obuf
  __shared__ __align__(16) unsigned short Tb[4][16][16];
  __shared__ __align__(16) unsigned short rtmp[64][16];
  __shared__ float Gar[64];
  __shared__ float gamv[64];
  __shared__ float barr[64];
  __shared__ float gcs[2];

  const int bid = blockIdx.x;
  const int b = bid >> 6;
  const int h = (bid >> 1) & 31;
  const int half = bid & 1;
  const int hk = h >> 1;
  const int t = threadIdx.x;
  const int wv = t >> 6, lane = t & 63;
  const int l16 = lane & 15, lg = lane >> 4;
  const int bS = b << 10;

  float4v accS[8] = {};
  for (int idx = t; idx < 64 * 128; idx += 256) (&Sb[0][0])[idx] = 0;

  for (int ch = 0; ch < 16; ch++) {
    const int s0 = ch << 6;
    // ---- phase 1: stage Kb, Qb (swizzled via source permutation), Vt, g/beta ----
    {
#pragma unroll
      for (int rep = 0; rep < 4; rep++) {
        int rb = wv * 16 + rep * 4;
        int i = rb + (lane >> 4);
        int cg = (lane & 15) ^ (i & 7);
        const unsigned short* gk = qkvs + (size_t)(bS + s0 + i) * 8192 + 2048 + hk * 128 + cg * 8;
        gl16(gk, (char*)(&Kb[rb][0] + lane * 8));
        const unsigned short* gq = qkvs + (size_t)(bS + s0 + i) * 8192 + hk * 128 + cg * 8;
        gl16(gq, (char*)(&Qb[rb][0] + lane * 8));
      }
    }
    {
      int tt = t >> 2, q4 = t & 3;
      const unsigned short* gv = qkvs + (size_t)(bS + s0 + tt) * 8192 + 4096 + h * 128 + half * 64 + q4 * 16;
      short8 v0 = *(const short8*)gv;
      short8 v1 = *(const short8*)(gv + 8);
#pragma unroll
      for (int e = 0; e < 8; e++) {
        int v = q4 * 16 + e;
        Vt[v][tt ^ ((v & 7) << 3)] = (unsigned short)v0[e];
        v = q4 * 16 + 8 + e;
        Vt[v][tt ^ ((v & 7) << 3)] = (unsigned short)v1[e];
      }
    }
    if (t < 64) {
      float gt = g[(bS + s0 + t) * 32 + h];
      float bt = bet[(bS + s0 + t) * 32 + h];
#pragma unroll
      for (int d = 1; d < 64; d <<= 1) {
        float o = __shfl_up(gt, d);
        if (t >= d) gt += o;
      }
      Gar[t] = gt;
      gamv[t] = __expf(gt);
      barr[t] = bt;
      if (t == 63) { gcs[0] = gt; gcs[1] = __expf(gt); }
    }
    __syncthreads();

    // ---- phase 2: KK^T -> Mb, QK^T -> Nb; build Ktt ----
    {
      float4v aK[4] = {}, aQ[4] = {};
      const int arow = wv * 16 + l16;
      const int asw = (arow & 7) << 3;
#pragma unroll
      for (int kk = 0; kk < 4; kk++) {
        short8 av = *(const short8*)&Kb[arow][(kk * 32 + lg * 8) ^ asw];
        short8 aq = *(const short8*)&Qb[arow][(kk * 32 + lg * 8) ^ asw];
#pragma unroll
        for (int j = 0; j < 4; j++) {
          int brow = j * 16 + l16;
          short8 bv = *(const short8*)&Kb[brow][(kk * 32 + lg * 8) ^ ((brow & 7) << 3)];
          aK[j] = MFMA32(av, bv, aK[j]);
          aQ[j] = MFMA32(aq, bv, aQ[j]);
        }
      }
#pragma unroll
      for (int j = 0; j < 4; j++) {
#pragma unroll
        for (int reg = 0; reg < 4; reg++) {
          int tt = wv * 16 + lg * 4 + reg;
          int ii = j * 16 + l16;
          float sc = __expf(Gar[tt] - Gar[ii]);
          float mv = (ii < tt) ? aK[j][reg] * barr[tt] * sc : 0.f;
          float nv = (ii <= tt) ? aQ[j][reg] * sc : 0.f;
          Mb[tt][(ii ^ ((tt & 7) << 3))] = f2b(mv);
          Nb[tt][(ii ^ ((tt & 7) << 3))] = f2b(nv);
        }
      }
    }
    {
      int i = t >> 2, q4 = t & 3;
      float sc = __expf(gcs[0] - Gar[i]);
      int isw = (i & 7) << 3;
#pragma unroll
      for (int e8 = 0; e8 < 4; e8++) {
        int d0 = q4 * 32 + e8 * 8;
        short8 kv = *(const short8*)&Kb[i][d0 ^ isw];
#pragma unroll
        for (int e = 0; e < 8; e++) {
          int d = d0 + e;
          Ktt[d][i ^ ((d & 7) << 3)] = f2b(b2f((unsigned short)kv[e]) * sc);
        }
      }
    }
    __syncthreads();

    // ---- phase 3: P0t = S0 K^T; RHS -> Dbf; T-inverse -> Tb ----
    {
      float4v acc[4] = {};
      const int arow = wv * 16 + l16;  // v
      const int asw = (arow & 7) << 3;
#pragma unroll
      for (int kk = 0; kk < 4; kk++) {
        short8 av = *(const short8*)&Sb[arow][(kk * 32 + lg * 8) ^ asw];
#pragma unroll
        for (int j = 0; j < 4; j++) {
          int brow = j * 16 + l16;  // t
          short8 bv = *(const short8*)&Kb[brow][(kk * 32 + lg * 8) ^ ((brow & 7) << 3)];
          acc[j] = MFMA32(av, bv, acc[j]);
        }
      }
#pragma unroll
      for (int j = 0; j < 4; j++) {
#pragma unroll
        for (int reg = 0; reg < 4; reg++) {
          int v = wv * 16 + lg * 4 + reg;
          int tt = j * 16 + l16;
          float vtv = b2f(Vt[v][tt ^ ((v & 7) << 3)]);
          float val = barr[tt] * (vtv - gamv[tt] * acc[j][reg]);
          Dbf[v][tt ^ ((v & 7) << 3)] = f2b(val);
        }
      }
    }
    {
      // T-inverse of diagonal block wv (unit lower)
      float Lrow[16];
#pragma unroll
      for (int i = 0; i < 16; i++)
        Lrow[i] = b2f(Mb[wv * 16 + l16][((wv * 16 + i) ^ ((l16 & 7) << 3))]);
      float Tc[16];
#pragma unroll
      for (int i = 0; i < 16; i++) Tc[i] = (i == l16) ? 1.f : 0.f;
#pragma unroll
      for (int tt = 1; tt < 16; tt++) {
        float s = 0.f;
#pragma unroll
        for (int i = 0; i < 16; i++) {
          if (i < tt)
            s += __int_as_float(__builtin_amdgcn_readlane(__float_as_int(Lrow[i]), tt)) * Tc[i];
        }
        Tc[tt] = ((tt == l16) ? 1.f : 0.f) - s;
      }
      if (lane < 16) {
#pragma unroll
        for (int tt = 0; tt < 16; tt++) Tb[wv][tt][l16] = f2b(Tc[tt]);
      }
    }
    __syncthreads();

    // ---- phase 4: block forward substitution, D = (I+M)^{-1} RHS ----
    {
      short8 a = (short8)(short)0, bT = (short8)(short)0;
      const int arow = wv * 16 + l16;
      if (lg < 2) {
        a = *(const short8*)&Dbf[arow][((lg * 8) ^ ((arow & 7) << 3))];
        bT = *(const short8*)&Tb[0][l16][lg * 8];
      }
      float4v acc0 = {};
      acc0 = MFMA32(a, bT, acc0);
      __syncthreads();
#pragma unroll
      for (int reg = 0; reg < 4; reg++) {
        int v = wv * 16 + lg * 4 + reg;
        Dbf[v][(l16 ^ ((v & 7) << 3))] = f2b(acc0[reg]);
      }
    }
    __syncthreads();
#pragma unroll
    for (int s = 1; s < 4; s++) {
      float4v acc = {};
      const int arow = wv * 16 + l16;
      const int mrow = s * 16 + l16;
#pragma unroll
      for (int j = 0; j < 3; j++) {
        if (j < s) {
          short8 a = (short8)(short)0, bM = (short8)(short)0;
          if (lg < 2) {
            a  = *(const short8*)&Dbf[arow][((j * 16 + lg * 8) ^ ((arow & 7) << 3))];
            bM = *(const short8*)&Mb[mrow][((j * 16 + lg * 8) ^ ((mrow & 7) << 3))];
          }
          acc = MFMA32(a, bM, acc);
        }
      }
#pragma unroll
      for (int reg = 0; reg < 4; reg++) {
        int v = wv * 16 + lg * 4 + reg;
        float rt = b2f(Dbf[v][((s * 16 + l16) ^ ((v & 7) << 3))]);
        rtmp[v][l16] = f2b(rt - acc[reg]);
      }
      __syncthreads();
      short8 a2 = (short8)(short)0, bT = (short8)(short)0;
      if (lg < 2) {
        a2 = *(const short8*)&rtmp[wv * 16 + l16][lg * 8];
        bT = *(const short8*)&Tb[s][l16][lg * 8];
      }
      float4v acc2 = {};
      acc2 = MFMA32(a2, bT, acc2);
      __syncthreads();
#pragma unroll
      for (int reg = 0; reg < 4; reg++) {
        int v = wv * 16 + lg * 4 + reg;
        Dbf[v][((s * 16 + l16) ^ ((v & 7) << 3))] = f2b(acc2[reg]);
      }
      __syncthreads();
    }

    // ---- phase 5: O = diag(gam) Q S0^T + N D ----
    {
      float4v acc[4] = {};
      const int arow = wv * 16 + l16;  // t
      const int asw = (arow & 7) << 3;
#pragma unroll
      for (int kk = 0; kk < 4; kk++) {
        short8 aq = *(const short8*)&Qb[arow][(kk * 32 + lg * 8) ^ asw];
#pragma unroll
        for (int j = 0; j < 4; j++) {
          int brow = j * 16 + l16;  // v
          short8 bs = *(const short8*)&Sb[brow][(kk * 32 + lg * 8) ^ ((brow & 7) << 3)];
          acc[j] = MFMA32(aq, bs, acc[j]);
        }
      }
#pragma unroll
      for (int j = 0; j < 4; j++) {
#pragma unroll
        for (int reg = 0; reg < 4; reg++) {
          int tt = wv * 16 + lg * 4 + reg;
          acc[j][reg] *= gamv[tt];
        }
      }
#pragma unroll
      for (int kk = 0; kk < 2; kk++) {
        short8 an = *(const short8*)&Nb[arow][(kk * 32 + lg * 8) ^ asw];
#pragma unroll
        for (int j = 0; j < 4; j++) {
          int brow = j * 16 + l16;  // v
          short8 bd = *(const short8*)&Dbf[brow][(kk * 32 + lg * 8) ^ ((brow & 7) << 3)];
          acc[j] = MFMA32(an, bd, acc[j]);
        }
      }
      __syncthreads();  // Vt consumed; reuse as obuf
#pragma unroll
      for (int j = 0; j < 4; j++) {
#pragma unroll
        for (int reg = 0; reg < 4; reg++) {
          int tt = wv * 16 + lg * 4 + reg;
          int v = j * 16 + l16;
          Vt[tt][v ^ ((tt & 7) << 3)] = f2b(acc[j][reg]);
        }
      }
    }
    __syncthreads();
    {
      int tt = t >> 2, q4 = t & 3;
      int sw = (tt & 7) << 3;
      unsigned short* yg = y + (size_t)(bS + s0 + tt) * 4096 + h * 128 + half * 64 + q4 * 16;
      short8 o0 = *(const short8*)&Vt[tt][(q4 * 16) ^ sw];
      short8 o1 = *(const short8*)&Vt[tt][(q4 * 16 + 8) ^ sw];
      *(short8*)yg = o0;
      *(short8*)(yg + 8) = o1;
    }

    // ---- phase 6: state update S = gamC * S + D^T Ktt ----
    {
      float gC = gcs[1];
#pragma unroll
      for (int dt = 0; dt < 8; dt++)
#pragma unroll
        for (int reg = 0; reg < 4; reg++) accS[dt][reg] *= gC;
      const int arow = wv * 16 + l16;  // v
      const int asw = (arow & 7) << 3;
#pragma unroll
      for (int kk = 0; kk < 2; kk++) {
        short8 ad = *(const short8*)&Dbf[arow][(kk * 32 + lg * 8) ^ asw];
#pragma unroll
        for (int dt = 0; dt < 8; dt++) {
          int brow = dt * 16 + l16;  // d
          short8 bk = *(const short8*)&Ktt[brow][(kk * 32 + lg * 8) ^ ((brow & 7) << 3)];
          accS[dt] = MFMA32(ad, bk, accS[dt]);
        }
      }
      __syncthreads();
#pragma unroll
      for (int dt = 0; dt < 8; dt++) {
#pragma unroll
        for (int reg = 0; reg < 4; reg++) {
          int v = wv * 16 + lg * 4 + reg;
          int d = dt * 16 + l16;
          Sb[v][d ^ ((v & 7) << 3)] = f2b(accS[dt][reg]);
        }
      }
    }
    __syncthreads();
  }

  // final state writeout (fp32)
#pragma unroll
  for (int dt = 0; dt < 8; dt++) {
#pragma unroll
    for (int reg = 0; reg < 4; reg++) {
      int v = wv * 16 + lg * 4 + reg;
      int d = dt * 16 + l16;
      state_out[((size_t)((b * 32 + h) * 128 + half * 64 + v)) * 128 + d] = accS[dt][reg];
    }
  }
}

// ---- RMSNorm over DV * norm_w * silu(z) -> yn bf16 ----
__global__ __launch_bounds__(256)
void rms_silu(const unsigned short* __restrict__ y, const unsigned short* __restrict__ qkvz,
              const float* __restrict__ nw, unsigned short* __restrict__ yn) {
  int m = blockIdx.x;
  int t = threadIdx.x;
  int head = t >> 3, oct = t & 7;
  int vb = head * 128 + oct * 16;
  const unsigned short* yp = y + (size_t)m * 4096 + vb;
  float yy[16];
  short8 y0 = *(const short8*)yp, y1 = *(const short8*)(yp + 8);
#pragma unroll
  for (int e = 0; e < 8; e++) { yy[e] = b2f((unsigned short)y0[e]); yy[8 + e] = b2f((unsigned short)y1[e]); }
  float ss = 0.f;
#pragma unroll
  for (int e = 0; e < 16; e++) ss += yy[e] * yy[e];
  ss += __shfl_xor(ss, 1); ss += __shfl_xor(ss, 2); ss += __shfl_xor(ss, 4);
  float rinv = rsqrtf(ss * (1.f / 128.f) + 1e-6f);
  const unsigned short* zp = qkvz + (size_t)m * NP + 8192 + vb;
  short8 z0 = *(const short8*)zp, z1 = *(const short8*)(zp + 8);
  short8 o0, o1;
#pragma unroll
  for (int e = 0; e < 8; e++) {
    float z = b2f((unsigned short)z0[e]);
    float v = nw[oct * 16 + e] * yy[e] * rinv * (z / (1.f + expf(-z)));
    o0[e] = (short)f2b(v);
    z = b2f((unsigned short)z1[e]);
    v = nw[oct * 16 + 8 + e] * yy[8 + e] * rinv * (z / (1.f + expf(-z)));
    o1[e] = (short)f2b(v);
  }
  unsigned short* op = yn + (size_t)m * 4096 + vb;
  *(short8*)op = o0;
  *(short8*)(op + 8) = o1;
}

extern "C" void kernel_launch(void* const* d_in, const int* in_sizes, int n_in,
                              void* d_out, int out_size, void* d_ws, size_t ws_size,
                              hipStream_t stream) {
  if (ws_size < WS_NEED) return;  // guard: fail with clean absmax, not a fault

  const float* x     = (const float*)d_in[0];
  const float* Wqkv  = (const float*)d_in[1];
  const float* Wz    = (const float*)d_in[2];
  const float* Wa    = (const float*)d_in[3];
  const float* Wb    = (const float*)d_in[4];
  const float* convw = (const float*)d_in[5];
  const float* Alog  = (const float*)d_in[6];
  const float* dtb   = (const float*)d_in[7];
  const float* nw    = (const float*)d_in[8];
  const float* Wout  = (const float*)d_in[9];

  char* ws = (char*)d_ws;
  unsigned short* qkvz = (unsigned short*)(ws + OFF_QKVZ);
  unsigned short* xb   = (unsigned short*)(ws + OFF_XB);
  unsigned short* wcat = (unsigned short*)(ws + OFF_WCAT);
  unsigned short* qkvs = (unsigned short*)(ws + OFF_QKVS);
  unsigned short* ynb  = (unsigned short*)(ws + OFF_YN);
  unsigned short* wob  = (unsigned short*)(ws + OFF_WOB);
  float* gbuf          = (float*)(ws + OFF_G);
  float* bbuf          = (float*)(ws + OFF_BET);

  float* outp       = (float*)d_out;
  float* conv_state = outp + 8388608;             // B*S*H
  float* state      = outp + 8388608 + 131072;    // + B*CI*KW
  unsigned short* ybuf = (unsigned short*)d_out;  // y bf16 scratch over outp region

  castk<<<8192, 256, 0, stream>>>(x, xb, 2097152);
  prep_wcat<<<25088, 256, 0, stream>>>(Wqkv, Wz, Wa, Wb, wcat);

  // GEMM1: bn-major XCD chunks (each XCD keeps a B-col slab near-L2-resident)
  gemm_pipe<256, true, unsigned short><<<784, 512, 0, stream>>>(xb, wcat, qkvz, 2048, 16, 49, NP);

  conv_silu_norm<<<256, 1024, 0, stream>>>(qkvz, convw, qkvs);
  conv_state_k<<<512, 256, 0, stream>>>(qkvz, conv_state);
  gb_kernel<<<1024, 256, 0, stream>>>(qkvz, Alog, dtb, gbuf, bbuf);

  scan_chunk<<<256, 256, 0, stream>>>(qkvs, gbuf, bbuf, ybuf, state);

  rms_silu<<<4096, 256, 0, stream>>>(ybuf, qkvz, nw, ynb);
  castk<<<8192, 256, 0, stream>>>(Wout, wob, 2097152);

  // GEMM2: BM=128 -> 256 blocks (all CUs busy), bm-major XCD chunks
  gemm_pipe<128, false, float><<<256, 512, 0, stream>>>(ynb, wob, outp, 4096, 32, 8, 2048);
}